// Round 6
// baseline (527.198 us; speedup 1.0000x reference)
//
#include <hip/hip_runtime.h>
#include <hip/hip_bf16.h>

// ---------------------------------------------------------------------------
// SmallthinkerAttention: hs->QKV proj -> RoPE -> causal attn (writes P) -> out proj
// B=2 S=2048 HID=2048 NH=32 NKV=8 HD=64
// d_out = [out (2*2048*2048 f32), attn_weights (2*32*2048*2048 f32)]
// R6: attn split into attn_sums (rowsums + zero-fill, K-dbuf, 1 barrier/tile)
//     and attn_store (P-write + PV). 8-wave blocks over 128-row stripe pairs
//     (qt, 15-qt): constant work/block, half the barrier-iterations of R5.
// ---------------------------------------------------------------------------

typedef __bf16 bf16;
typedef bf16 bf16x8 __attribute__((ext_vector_type(8)));
typedef bf16 bf16x4 __attribute__((ext_vector_type(4)));
typedef float f32x4 __attribute__((ext_vector_type(4)));

#define B_   2
#define S_   2048
#define HID_ 2048
#define NH_  32
#define NKV_ 8
#define HD_  64
#define TOK_ (B_*S_)          // 4096
#define QKVN 3072             // fused QKV output cols: 2048 q | 512 k | 512 v

// async global->LDS, 16B per lane, LDS dest = wave-uniform base + lane*16
__device__ __forceinline__ void gl_lds16(const bf16* g, bf16* l) {
  __builtin_amdgcn_global_load_lds(
      (const __attribute__((address_space(1))) unsigned int*)(g),
      (__attribute__((address_space(3))) unsigned int*)(l), 16, 0, 0);
}

// ---------------- cast f32 -> bf16 (vectorized) ----------------
__global__ __launch_bounds__(256) void cast_f32_bf16(const float* __restrict__ in,
                                                     bf16* __restrict__ out, int n4) {
  int i = blockIdx.x * 256 + threadIdx.x;
  if (i >= n4) return;
  f32x4 v = ((const f32x4*)in)[i];
  bf16x4 o;
  o[0] = (bf16)v[0]; o[1] = (bf16)v[1]; o[2] = (bf16)v[2]; o[3] = (bf16)v[3];
  ((bf16x4*)out)[i] = o;
}

// fused Wq|Wk|Wv cast into contiguous Wqkv (rows: 2048 q | 512 k | 512 v)
__global__ __launch_bounds__(256) void cast_wqkv(const float* __restrict__ wq,
                                                 const float* __restrict__ wk,
                                                 const float* __restrict__ wv,
                                                 bf16* __restrict__ dst) {
  int i = blockIdx.x * 256 + threadIdx.x;      // 0 .. 1572863 (x4 units)
  const float* src; int off;
  if (i < 1048576)      { src = wq; off = i; }
  else if (i < 1310720) { src = wk; off = i - 1048576; }
  else                  { src = wv; off = i - 1310720; }
  f32x4 v = ((const f32x4*)src)[off];
  bf16x4 o;
  o[0] = (bf16)v[0]; o[1] = (bf16)v[1]; o[2] = (bf16)v[2]; o[3] = (bf16)v[3];
  ((bf16x4*)dst)[i] = o;
}

// ---------------- GEMM: C[M,N] = A[M,K] @ B[N,K]^T  (bf16 in, bf16/f32 out) ----
// m97 structure + T1 XCD swizzle. Linear LDS (required by global_load_lds).
template<bool OUT_F32>
__global__ __launch_bounds__(256) void gemm_bt(const bf16* __restrict__ A,
                                               const bf16* __restrict__ Bm,
                                               void* __restrict__ Cout,
                                               int M, int N, int K) {
  __shared__ __align__(16) bf16 As[128 * 32];
  __shared__ __align__(16) bf16 Bs[128 * 32];
  const int tid  = threadIdx.x;
  const int wave = tid >> 6, lane = tid & 63;

  // T1 XCD-aware swizzle (nwg % 8 == 0 for all our launches)
  const int nwg = (int)(gridDim.x * gridDim.y);
  const int bid = (int)(blockIdx.y * gridDim.x + blockIdx.x);
  const int swz = (bid & 7) * (nwg >> 3) + (bid >> 3);
  const int bx = swz % (int)gridDim.x, by = swz / (int)gridDim.x;

  const int bm = by * 128, bn = bx * 128;
  const int wm = (wave >> 1) * 64, wn = (wave & 1) * 64;
  const int fr = lane & 15, fg = lane >> 4;

  const int r0   = wave * 32 + (lane >> 2);
  const int scol = (lane & 3) * 8;
  const bf16* ga0 = A  + (size_t)(bm + r0) * K + scol;
  const bf16* ga1 = ga0 + (size_t)16 * K;
  const bf16* gb0 = Bm + (size_t)(bn + r0) * K + scol;
  const bf16* gb1 = gb0 + (size_t)16 * K;
  bf16* lA0 = As + (wave * 32) * 32;
  bf16* lA1 = lA0 + 16 * 32;
  bf16* lB0 = Bs + (wave * 32) * 32;
  bf16* lB1 = lB0 + 16 * 32;

  f32x4 acc[4][4] = {};

  for (int k0 = 0; k0 < K; k0 += 32) {
    gl_lds16(ga0 + k0, lA0);
    gl_lds16(ga1 + k0, lA1);
    gl_lds16(gb0 + k0, lB0);
    gl_lds16(gb1 + k0, lB1);
    __syncthreads();
    bf16x8 af[4], bfv[4];
#pragma unroll
    for (int i = 0; i < 4; ++i) {
      af[i]  = *(const bf16x8*)&As[(wm + i * 16 + fr) * 32 + fg * 8];
      bfv[i] = *(const bf16x8*)&Bs[(wn + i * 16 + fr) * 32 + fg * 8];
    }
#pragma unroll
    for (int i = 0; i < 4; ++i)
#pragma unroll
      for (int j = 0; j < 4; ++j)
        acc[i][j] = __builtin_amdgcn_mfma_f32_16x16x32_bf16(af[i], bfv[j], acc[i][j], 0, 0, 0);
    __syncthreads();
  }

#pragma unroll
  for (int i = 0; i < 4; ++i)
#pragma unroll
    for (int j = 0; j < 4; ++j)
#pragma unroll
      for (int r = 0; r < 4; ++r) {
        int row = bm + wm + i * 16 + fg * 4 + r;
        int col = bn + wn + j * 16 + fr;
        float v = acc[i][j][r];
        if (OUT_F32) __builtin_nontemporal_store(v, &((float*)Cout)[(size_t)row * N + col]);
        else         ((bf16*)Cout)[(size_t)row * N + col] = (bf16)v;
      }
}

// ---------------- RoPE: one block per token, q (32 heads) + k (8 heads) ------
__global__ __launch_bounds__(256) void rope_fused(bf16* __restrict__ qkv,
                                                  const float* __restrict__ cosp,
                                                  const float* __restrict__ sinp) {
  const int t = blockIdx.x;                    // 0..TOK-1
  const int tid = threadIdx.x;
  const int d = tid & 31, g = tid >> 5;        // g 0..7
  const float c = cosp[t * 64 + d];
  const float s = sinp[t * 64 + d];
  bf16* row = qkv + (size_t)t * QKVN;
#pragma unroll
  for (int i = 0; i < 4; ++i) {
    bf16* p = row + (g + i * 8) * 64 + d;      // q heads
    float x1 = (float)p[0], x2 = (float)p[32];
    p[0]  = (bf16)(x1 * c - x2 * s);
    p[32] = (bf16)(x2 * c + x1 * s);
  }
  bf16* p = row + 2048 + g * 64 + d;           // k head
  float x1 = (float)p[0], x2 = (float)p[32];
  p[0]  = (bf16)(x1 * c - x2 * s);
  p[32] = (bf16)(x2 * c + x1 * s);
}

// ---------------- transpose V: qkv v-cols -> vT[(b*8+kv)][64][2048] ----------
__global__ __launch_bounds__(256) void transpose_v(const bf16* __restrict__ v,  // qkv + 2560
                                                   bf16* __restrict__ vT) {
  __shared__ __align__(16) bf16 t[64][72];
  const int bkv = blockIdx.y;
  const int b = bkv >> 3, kv = bkv & 7;
  const int s0 = blockIdx.x * 64;
  const int tid = threadIdx.x;
  const int r = tid >> 3, c = (tid & 7) * 8;
#pragma unroll
  for (int p = 0; p < 2; ++p) {
    int rr = r + p * 32;
    *(bf16x8*)&t[rr][c] = *(const bf16x8*)&v[(size_t)(b * S_ + s0 + rr) * QKVN + kv * 64 + c];
  }
  __syncthreads();
#pragma unroll
  for (int p = 0; p < 2; ++p) {
    int d = r + p * 32;
    bf16x8 o;
#pragma unroll
    for (int j = 0; j < 8; ++j) o[j] = t[c + j][d];
    *(bf16x8*)&vT[((size_t)bkv * 64 + d) * S_ + s0 + c] = o;
  }
}

// ---------------- attn pass 1: rowsums (+ zero-fill of masked attnw) --------
// block (qt 0..7, bh 0..63): stripes LO = qt*128, HI = (15-qt)*128. 8 waves,
// wave w rows [w*16, w*16+16) in both stripes. NT = 32-2qt K-tiles (64 rows).
// K double-buffered in LDS: ONE barrier per tile. Writes 1/rowsum to rs_buf.
__global__ __launch_bounds__(512, 4) void attn_sums(const bf16* __restrict__ qkv,
                                                    float* __restrict__ rs_buf,   // (64, S)
                                                    float* __restrict__ attnw)    // (64, S, S)
{
  __shared__ __align__(16) bf16 Ks2[2][64][72];

  const int tid  = threadIdx.x;
  const int wave = tid >> 6, lane = tid & 63;
  const int qt = blockIdx.x;                   // 0..7
  const int bh = blockIdx.y;                   // 0..63
  const int b = bh >> 5, h = bh & 31, kv = h >> 2;
  const int qLo = qt * 128;
  const int qHi = (15 - qt) * 128;
  const int NT  = 32 - 2 * qt;                 // K tiles needed by HI
  const int loNT = 2 * qt + 2;                 // LO participates for jt < loNT
  const int fr = lane & 15, fg = lane >> 4;
  const int rw = wave * 16;
  const int rt = rw + fg * 4;

  // Q fragments for both stripes
  bf16x8 aqL[2], aqH[2];
  {
    const bf16* qp = qkv + (size_t)(b * S_ + qLo + rw + fr) * QKVN + h * 64 + fg * 8;
    aqL[0] = *(const bf16x8*)qp;  aqL[1] = *(const bf16x8*)(qp + 32);
    qp = qkv + (size_t)(b * S_ + qHi + rw + fr) * QKVN + h * 64 + fg * 8;
    aqH[0] = *(const bf16x8*)qp;  aqH[1] = *(const bf16x8*)(qp + 32);
  }

  // staging: 512 threads x 8 elems = 64x64 tile
  const int lr = tid >> 3;                     // 0..63
  const int lc = (tid & 7) * 8;                // 0..56
  const bf16* kst = qkv + (size_t)(b * S_) * QKVN + 2048 + kv * 64
                        + (size_t)lr * QKVN + lc;

  float rsL[4] = {0.f,0.f,0.f,0.f}, rsH[4] = {0.f,0.f,0.f,0.f};

  // prologue: tile 0 -> buf 0
  bf16x8 kr = *(const bf16x8*)(kst);
  *(bf16x8*)&Ks2[0][lr][lc] = kr;
  __syncthreads();

  for (int jt = 0; jt < NT; ++jt) {
    const int cur = jt & 1;
    if (jt + 1 < NT) kr = *(const bf16x8*)(kst + (size_t)(jt + 1) * 64 * QKVN);
    const int j0 = jt * 64;

    // ---- HI stripe ----
    {
      const int dj = j0 - qHi;
      if (dj <= rw + 15) {                     // not fullmask (wave-uniform)
        f32x4 acc[4] = {};
#pragma unroll
        for (int nn = 0; nn < 4; ++nn) {
          bf16x8 bk0 = *(const bf16x8*)&Ks2[cur][nn*16 + fr][fg*8];
          bf16x8 bk1 = *(const bf16x8*)&Ks2[cur][nn*16 + fr][32 + fg*8];
          acc[nn] = __builtin_amdgcn_mfma_f32_16x16x32_bf16(aqH[0], bk0, acc[nn], 0, 0, 0);
          acc[nn] = __builtin_amdgcn_mfma_f32_16x16x32_bf16(aqH[1], bk1, acc[nn], 0, 0, 0);
        }
        if (dj + 63 <= rw) {                   // fully unmasked
#pragma unroll
          for (int nn = 0; nn < 4; ++nn)
#pragma unroll
            for (int r = 0; r < 4; ++r) rsH[r] += __expf(acc[nn][r] * 0.125f);
        } else {                               // diagonal
#pragma unroll
          for (int nn = 0; nn < 4; ++nn)
#pragma unroll
            for (int r = 0; r < 4; ++r)
              if (dj + nn * 16 + fr <= rt + r) rsH[r] += __expf(acc[nn][r] * 0.125f);
        }
      }
    }
    // ---- LO stripe ----
    if (jt < loNT) {
      const int dj = j0 - qLo;
      if (dj <= rw + 15) {
        f32x4 acc[4] = {};
#pragma unroll
        for (int nn = 0; nn < 4; ++nn) {
          bf16x8 bk0 = *(const bf16x8*)&Ks2[cur][nn*16 + fr][fg*8];
          bf16x8 bk1 = *(const bf16x8*)&Ks2[cur][nn*16 + fr][32 + fg*8];
          acc[nn] = __builtin_amdgcn_mfma_f32_16x16x32_bf16(aqL[0], bk0, acc[nn], 0, 0, 0);
          acc[nn] = __builtin_amdgcn_mfma_f32_16x16x32_bf16(aqL[1], bk1, acc[nn], 0, 0, 0);
        }
        if (dj + 63 <= rw) {
#pragma unroll
          for (int nn = 0; nn < 4; ++nn)
#pragma unroll
            for (int r = 0; r < 4; ++r) rsL[r] += __expf(acc[nn][r] * 0.125f);
        } else {
#pragma unroll
          for (int nn = 0; nn < 4; ++nn)
#pragma unroll
            for (int r = 0; r < 4; ++r)
              if (dj + nn * 16 + fr <= rt + r) rsL[r] += __expf(acc[nn][r] * 0.125f);
        }
      }
    }

    if (jt + 1 < NT) *(bf16x8*)&Ks2[cur ^ 1][lr][lc] = kr;
    __syncthreads();
  }

  // reduce over the 16 col-lanes, store inverted
#pragma unroll
  for (int r = 0; r < 4; ++r) {
    float v = rsL[r];
    v += __shfl_xor(v, 1); v += __shfl_xor(v, 2);
    v += __shfl_xor(v, 4); v += __shfl_xor(v, 8);
    if (fr == 0) rs_buf[(size_t)bh * S_ + qLo + rt + r] = 1.0f / v;
    v = rsH[r];
    v += __shfl_xor(v, 1); v += __shfl_xor(v, 2);
    v += __shfl_xor(v, 4); v += __shfl_xor(v, 8);
    if (fr == 0) rs_buf[(size_t)bh * S_ + qHi + rt + r] = 1.0f / v;
  }

  // zero-fill masked attnw regions (overlaps this kernel's compute-only phase)
  {
    f32x4 z4 = {0.f, 0.f, 0.f, 0.f};
    const int zLo = loNT * 64;                 // LO rows: cols [zLo, S)
    for (int rr = 0; rr < 16; ++rr) {
      size_t base = ((size_t)bh * S_ + qLo + rw + rr) * S_;
      for (int c = zLo + lane * 4; c < S_; c += 256)
        __builtin_nontemporal_store(z4, (f32x4*)&attnw[base + c]);
    }
    const int zHi = NT * 64;                   // HI rows: cols [zHi, S)
    for (int rr = 0; rr < 16; ++rr) {
      size_t base = ((size_t)bh * S_ + qHi + rw + rr) * S_;
      for (int c = zHi + lane * 4; c < S_; c += 256)
        __builtin_nontemporal_store(z4, (f32x4*)&attnw[base + c]);
    }
  }
}

// ---------------- attn pass 2: P write + PV accumulate ----------------
// Same decomposition as attn_sums. Reads 1/rowsum from rs_buf.
__global__ __launch_bounds__(512, 4) void attn_store(const bf16* __restrict__ qkv,
                                                     const bf16* __restrict__ vT,
                                                     const float* __restrict__ rs_buf,
                                                     float* __restrict__ attnw,
                                                     bf16* __restrict__ attn_out)
{
  __shared__ __align__(16) bf16 Ks[64][72];
  __shared__ __align__(16) bf16 Vs[64][72];
  __shared__ __align__(16) bf16 Ps[8][16][72];

  const int tid  = threadIdx.x;
  const int wave = tid >> 6, lane = tid & 63;
  const int qt = blockIdx.x;                   // 0..7
  const int bh = blockIdx.y;                   // 0..63
  const int b = bh >> 5, h = bh & 31, kv = h >> 2;
  const int qLo = qt * 128;
  const int qHi = (15 - qt) * 128;
  const int NT  = 32 - 2 * qt;
  const int loNT = 2 * qt + 2;
  const int fr = lane & 15, fg = lane >> 4;
  const int rw = wave * 16;
  const int rt = rw + fg * 4;

  bf16x8 aqL[2], aqH[2];
  {
    const bf16* qp = qkv + (size_t)(b * S_ + qLo + rw + fr) * QKVN + h * 64 + fg * 8;
    aqL[0] = *(const bf16x8*)qp;  aqL[1] = *(const bf16x8*)(qp + 32);
    qp = qkv + (size_t)(b * S_ + qHi + rw + fr) * QKVN + h * 64 + fg * 8;
    aqH[0] = *(const bf16x8*)qp;  aqH[1] = *(const bf16x8*)(qp + 32);
  }

  float rsL[4], rsH[4];
#pragma unroll
  for (int r = 0; r < 4; ++r) {
    rsL[r] = rs_buf[(size_t)bh * S_ + qLo + rt + r];
    rsH[r] = rs_buf[(size_t)bh * S_ + qHi + rt + r];
  }

  const int lr = tid >> 3;                     // 0..63
  const int lc = (tid & 7) * 8;                // 0..56
  const bf16* kst = qkv + (size_t)(b * S_) * QKVN + 2048 + kv * 64
                        + (size_t)lr * QKVN + lc;
  const bf16* vst = vT + (size_t)(b * NKV_ + kv) * 64 * S_ + (size_t)lr * S_ + lc;

  float* awpL = attnw + ((size_t)bh * S_ + qLo + rt) * S_ + fr;
  float* awpH = attnw + ((size_t)bh * S_ + qHi + rt) * S_ + fr;

  f32x4 oL[4] = {}, oH[4] = {};

  bf16x8 kr = *(const bf16x8*)(kst);           // prefetch tile 0
  bf16x8 vr = *(const bf16x8*)(vst);

  for (int jt = 0; jt < NT; ++jt) {
    const int j0 = jt * 64;
    __syncthreads();
    *(bf16x8*)&Ks[lr][lc] = kr;
    *(bf16x8*)&Vs[lr][lc] = vr;
    __syncthreads();
    if (jt + 1 < NT) {
      kr = *(const bf16x8*)(kst + (size_t)(jt + 1) * 64 * QKVN);
      vr = *(const bf16x8*)(vst + (size_t)(jt + 1) * 64);
    }

    // ---- HI stripe (tiles [0,NT)) ----
    {
      const int dj = j0 - qHi;
      if (dj > rw + 15) {                      // fullmask: write zero P tile
#pragma unroll
        for (int nn = 0; nn < 4; ++nn)
#pragma unroll
          for (int r = 0; r < 4; ++r)
            __builtin_nontemporal_store(0.f, awpH + (size_t)r * S_ + nn * 16);
      } else {
        f32x4 acc[4] = {};
#pragma unroll
        for (int nn = 0; nn < 4; ++nn) {
          bf16x8 bk0 = *(const bf16x8*)&Ks[nn*16 + fr][fg*8];
          bf16x8 bk1 = *(const bf16x8*)&Ks[nn*16 + fr][32 + fg*8];
          acc[nn] = __builtin_amdgcn_mfma_f32_16x16x32_bf16(aqH[0], bk0, acc[nn], 0, 0, 0);
          acc[nn] = __builtin_amdgcn_mfma_f32_16x16x32_bf16(aqH[1], bk1, acc[nn], 0, 0, 0);
        }
        if (dj + 63 <= rw) {
#pragma unroll
          for (int nn = 0; nn < 4; ++nn)
#pragma unroll
            for (int r = 0; r < 4; ++r) {
              float pv = __expf(acc[nn][r] * 0.125f) * rsH[r];
              __builtin_nontemporal_store(pv, awpH + (size_t)r * S_ + nn * 16);
              Ps[wave][fg * 4 + r][nn * 16 + fr] = (bf16)pv;
            }
        } else {
#pragma unroll
          for (int nn = 0; nn < 4; ++nn)
#pragma unroll
            for (int r = 0; r < 4; ++r) {
              float pv = (dj + nn * 16 + fr > rt + r) ? 0.f
                         : __expf(acc[nn][r] * 0.125f) * rsH[r];
              __builtin_nontemporal_store(pv, awpH + (size_t)r * S_ + nn * 16);
              Ps[wave][fg * 4 + r][nn * 16 + fr] = (bf16)pv;
            }
        }
        bf16x8 pa0 = *(const bf16x8*)&Ps[wave][fr][fg * 8];
        bf16x8 pa1 = *(const bf16x8*)&Ps[wave][fr][32 + fg * 8];
#pragma unroll
        for (int nn = 0; nn < 4; ++nn) {
          bf16x8 bv0 = *(const bf16x8*)&Vs[nn*16 + fr][fg*8];
          bf16x8 bv1 = *(const bf16x8*)&Vs[nn*16 + fr][32 + fg*8];
          oH[nn] = __builtin_amdgcn_mfma_f32_16x16x32_bf16(pa0, bv0, oH[nn], 0, 0, 0);
          oH[nn] = __builtin_amdgcn_mfma_f32_16x16x32_bf16(pa1, bv1, oH[nn], 0, 0, 0);
        }
      }
      awpH += 64;
    }
    // ---- LO stripe (tiles [0, loNT)) ----
    if (jt < loNT) {
      const int dj = j0 - qLo;
      if (dj > rw + 15) {
#pragma unroll
        for (int nn = 0; nn < 4; ++nn)
#pragma unroll
          for (int r = 0; r < 4; ++r)
            __builtin_nontemporal_store(0.f, awpL + (size_t)r * S_ + nn * 16);
      } else {
        f32x4 acc[4] = {};
#pragma unroll
        for (int nn = 0; nn < 4; ++nn) {
          bf16x8 bk0 = *(const bf16x8*)&Ks[nn*16 + fr][fg*8];
          bf16x8 bk1 = *(const bf16x8*)&Ks[nn*16 + fr][32 + fg*8];
          acc[nn] = __builtin_amdgcn_mfma_f32_16x16x32_bf16(aqL[0], bk0, acc[nn], 0, 0, 0);
          acc[nn] = __builtin_amdgcn_mfma_f32_16x16x32_bf16(aqL[1], bk1, acc[nn], 0, 0, 0);
        }
        if (dj + 63 <= rw) {
#pragma unroll
          for (int nn = 0; nn < 4; ++nn)
#pragma unroll
            for (int r = 0; r < 4; ++r) {
              float pv = __expf(acc[nn][r] * 0.125f) * rsL[r];
              __builtin_nontemporal_store(pv, awpL + (size_t)r * S_ + nn * 16);
              Ps[wave][fg * 4 + r][nn * 16 + fr] = (bf16)pv;
            }
        } else {
#pragma unroll
          for (int nn = 0; nn < 4; ++nn)
#pragma unroll
            for (int r = 0; r < 4; ++r) {
              float pv = (dj + nn * 16 + fr > rt + r) ? 0.f
                         : __expf(acc[nn][r] * 0.125f) * rsL[r];
              __builtin_nontemporal_store(pv, awpL + (size_t)r * S_ + nn * 16);
              Ps[wave][fg * 4 + r][nn * 16 + fr] = (bf16)pv;
            }
        }
        bf16x8 pa0 = *(const bf16x8*)&Ps[wave][fr][fg * 8];
        bf16x8 pa1 = *(const bf16x8*)&Ps[wave][fr][32 + fg * 8];
#pragma unroll
        for (int nn = 0; nn < 4; ++nn) {
          bf16x8 bv0 = *(const bf16x8*)&Vs[nn*16 + fr][fg*8];
          bf16x8 bv1 = *(const bf16x8*)&Vs[nn*16 + fr][32 + fg*8];
          oL[nn] = __builtin_amdgcn_mfma_f32_16x16x32_bf16(pa0, bv0, oL[nn], 0, 0, 0);
          oL[nn] = __builtin_amdgcn_mfma_f32_16x16x32_bf16(pa1, bv1, oL[nn], 0, 0, 0);
        }
      }
      awpL += 64;
    }
  }

  // attn_out (bf16) for both stripes
#pragma unroll
  for (int nn = 0; nn < 4; ++nn)
#pragma unroll
    for (int r = 0; r < 4; ++r) {
      int rowL = qLo + rt + r;
      int rowH = qHi + rt + r;
      attn_out[(size_t)(b * S_ + rowL) * (NH_*HD_) + h * 64 + nn * 16 + fr] = (bf16)oL[nn][r];
      attn_out[(size_t)(b * S_ + rowH) * (NH_*HD_) + h * 64 + nn * 16 + fr] = (bf16)oH[nn][r];
    }
}

// ---------------------------------------------------------------------------
extern "C" void kernel_launch(void* const* d_in, const int* in_sizes, int n_in,
                              void* d_out, int out_size, void* d_ws, size_t ws_size,
                              hipStream_t stream) {
  const float* hs   = (const float*)d_in[0];
  const float* cosp = (const float*)d_in[1];
  const float* sinp = (const float*)d_in[2];
  // d_in[3] = attention_mask (causal; applied analytically)
  const float* Wq = (const float*)d_in[4];
  const float* Wk = (const float*)d_in[5];
  const float* Wv = (const float*)d_in[6];
  const float* Wo = (const float*)d_in[7];

  char* ws = (char*)d_ws;
  bf16* hs_b   = (bf16*)(ws);                   // 16 MB
  bf16* qkv_b  = (bf16*)(ws + (16u << 20));     // 24 MB (TOK x 3072)
  bf16* vT_b   = (bf16*)(ws + (40u << 20));     // 4 MB
  bf16* ao_b   = (bf16*)(ws + (44u << 20));     // 16 MB
  bf16* Wqkv_b = (bf16*)(ws + (60u << 20));     // 12 MB (3072 x 2048)
  bf16* Wo_b   = (bf16*)(ws + (72u << 20));     // 8 MB
  float* rs_b  = (float*)(ws + (80u << 20));    // 512 KB (64 x 2048 f32)

  float* outp  = (float*)d_out;
  float* attnw = outp + (size_t)TOK_ * HID_;    // + 8388608

  // casts to bf16
  cast_f32_bf16<<<(TOK_*HID_/4 + 255)/256, 256, 0, stream>>>(hs, hs_b, TOK_*HID_/4);
  cast_wqkv<<<(1572864 + 255)/256, 256, 0, stream>>>(Wq, Wk, Wv, Wqkv_b);
  cast_f32_bf16<<<(HID_*NH_*HD_/4 + 255)/256, 256, 0, stream>>>(Wo, Wo_b, HID_*NH_*HD_/4);

  // fused QKV projection: (TOK,2048) @ (3072,2048)^T -> (TOK,3072)
  gemm_bt<false><<<dim3(QKVN/128, TOK_/128), 256, 0, stream>>>(hs_b, Wqkv_b, qkv_b, TOK_, QKVN, HID_);

  // RoPE (in place, one block per token)
  rope_fused<<<TOK_, 256, 0, stream>>>(qkv_b, cosp, sinp);

  // V transpose for PV B-operand contiguity
  transpose_v<<<dim3(S_/64, B_*NKV_), 256, 0, stream>>>(qkv_b + 2560, vT_b);

  // attn pass 1: rowsums + zero-fill
  attn_sums<<<dim3(8, B_*NH_), 512, 0, stream>>>(qkv_b, rs_b, attnw);

  // attn pass 2: P write + PV
  attn_store<<<dim3(8, B_*NH_), 512, 0, stream>>>(qkv_b, vT_b, rs_b, attnw, ao_b);

  // output projection (f32 out, nontemporal C stores)
  gemm_bt<true><<<dim3(HID_/128, TOK_/128), 256, 0, stream>>>(ao_b, Wo_b, outp, TOK_, HID_, HID_);
}

// Round 7
// 446.015 us; speedup vs baseline: 1.1820x; 1.1820x over previous
//
#include <hip/hip_runtime.h>
#include <hip/hip_bf16.h>

// ---------------------------------------------------------------------------
// SmallthinkerAttention: hs->QKV proj -> RoPE -> causal attn (writes P) -> out proj
// B=2 S=2048 HID=2048 NH=32 NKV=8 HD=64
// d_out = [out (2*2048*2048 f32), attn_weights (2*32*2048*2048 f32)]
// R7: revert to R5 structure (R6 split regressed). attn now uses SWAPPED QK^T
//     (S^T = mfma(K,Q)): lane holds 4 consecutive P columns -> P written as
//     f32x4 (4 stores/tile vs 16 scalars), plain cached stores (NT kept only
//     on the coalesced zero-fill). Out-proj C stores also non-NT.
// ---------------------------------------------------------------------------

typedef __bf16 bf16;
typedef bf16 bf16x8 __attribute__((ext_vector_type(8)));
typedef bf16 bf16x4 __attribute__((ext_vector_type(4)));
typedef float f32x4 __attribute__((ext_vector_type(4)));

#define B_   2
#define S_   2048
#define HID_ 2048
#define NH_  32
#define NKV_ 8
#define HD_  64
#define TOK_ (B_*S_)          // 4096
#define QKVN 3072             // fused QKV output cols: 2048 q | 512 k | 512 v

// async global->LDS, 16B per lane, LDS dest = wave-uniform base + lane*16
__device__ __forceinline__ void gl_lds16(const bf16* g, bf16* l) {
  __builtin_amdgcn_global_load_lds(
      (const __attribute__((address_space(1))) unsigned int*)(g),
      (__attribute__((address_space(3))) unsigned int*)(l), 16, 0, 0);
}

// ---------------- cast f32 -> bf16 (vectorized) ----------------
__global__ __launch_bounds__(256) void cast_f32_bf16(const float* __restrict__ in,
                                                     bf16* __restrict__ out, int n4) {
  int i = blockIdx.x * 256 + threadIdx.x;
  if (i >= n4) return;
  f32x4 v = ((const f32x4*)in)[i];
  bf16x4 o;
  o[0] = (bf16)v[0]; o[1] = (bf16)v[1]; o[2] = (bf16)v[2]; o[3] = (bf16)v[3];
  ((bf16x4*)out)[i] = o;
}

// fused Wq|Wk|Wv cast into contiguous Wqkv (rows: 2048 q | 512 k | 512 v)
__global__ __launch_bounds__(256) void cast_wqkv(const float* __restrict__ wq,
                                                 const float* __restrict__ wk,
                                                 const float* __restrict__ wv,
                                                 bf16* __restrict__ dst) {
  int i = blockIdx.x * 256 + threadIdx.x;      // 0 .. 1572863 (x4 units)
  const float* src; int off;
  if (i < 1048576)      { src = wq; off = i; }
  else if (i < 1310720) { src = wk; off = i - 1048576; }
  else                  { src = wv; off = i - 1310720; }
  f32x4 v = ((const f32x4*)src)[off];
  bf16x4 o;
  o[0] = (bf16)v[0]; o[1] = (bf16)v[1]; o[2] = (bf16)v[2]; o[3] = (bf16)v[3];
  ((bf16x4*)dst)[i] = o;
}

// ---------------- GEMM: C[M,N] = A[M,K] @ B[N,K]^T  (bf16 in, bf16/f32 out) ----
// m97 structure + T1 XCD swizzle. Linear LDS (required by global_load_lds).
template<bool OUT_F32>
__global__ __launch_bounds__(256) void gemm_bt(const bf16* __restrict__ A,
                                               const bf16* __restrict__ Bm,
                                               void* __restrict__ Cout,
                                               int M, int N, int K) {
  __shared__ __align__(16) bf16 As[128 * 32];
  __shared__ __align__(16) bf16 Bs[128 * 32];
  const int tid  = threadIdx.x;
  const int wave = tid >> 6, lane = tid & 63;

  // T1 XCD-aware swizzle (nwg % 8 == 0 for all our launches)
  const int nwg = (int)(gridDim.x * gridDim.y);
  const int bid = (int)(blockIdx.y * gridDim.x + blockIdx.x);
  const int swz = (bid & 7) * (nwg >> 3) + (bid >> 3);
  const int bx = swz % (int)gridDim.x, by = swz / (int)gridDim.x;

  const int bm = by * 128, bn = bx * 128;
  const int wm = (wave >> 1) * 64, wn = (wave & 1) * 64;
  const int fr = lane & 15, fg = lane >> 4;

  const int r0   = wave * 32 + (lane >> 2);
  const int scol = (lane & 3) * 8;
  const bf16* ga0 = A  + (size_t)(bm + r0) * K + scol;
  const bf16* ga1 = ga0 + (size_t)16 * K;
  const bf16* gb0 = Bm + (size_t)(bn + r0) * K + scol;
  const bf16* gb1 = gb0 + (size_t)16 * K;
  bf16* lA0 = As + (wave * 32) * 32;
  bf16* lA1 = lA0 + 16 * 32;
  bf16* lB0 = Bs + (wave * 32) * 32;
  bf16* lB1 = lB0 + 16 * 32;

  f32x4 acc[4][4] = {};

  for (int k0 = 0; k0 < K; k0 += 32) {
    gl_lds16(ga0 + k0, lA0);
    gl_lds16(ga1 + k0, lA1);
    gl_lds16(gb0 + k0, lB0);
    gl_lds16(gb1 + k0, lB1);
    __syncthreads();
    bf16x8 af[4], bfv[4];
#pragma unroll
    for (int i = 0; i < 4; ++i) {
      af[i]  = *(const bf16x8*)&As[(wm + i * 16 + fr) * 32 + fg * 8];
      bfv[i] = *(const bf16x8*)&Bs[(wn + i * 16 + fr) * 32 + fg * 8];
    }
#pragma unroll
    for (int i = 0; i < 4; ++i)
#pragma unroll
      for (int j = 0; j < 4; ++j)
        acc[i][j] = __builtin_amdgcn_mfma_f32_16x16x32_bf16(af[i], bfv[j], acc[i][j], 0, 0, 0);
    __syncthreads();
  }

#pragma unroll
  for (int i = 0; i < 4; ++i)
#pragma unroll
    for (int j = 0; j < 4; ++j)
#pragma unroll
      for (int r = 0; r < 4; ++r) {
        int row = bm + wm + i * 16 + fg * 4 + r;
        int col = bn + wn + j * 16 + fr;
        float v = acc[i][j][r];
        if (OUT_F32) ((float*)Cout)[(size_t)row * N + col] = v;
        else         ((bf16*)Cout)[(size_t)row * N + col] = (bf16)v;
      }
}

// ---------------- RoPE: one block per token, q (32 heads) + k (8 heads) ------
__global__ __launch_bounds__(256) void rope_fused(bf16* __restrict__ qkv,
                                                  const float* __restrict__ cosp,
                                                  const float* __restrict__ sinp) {
  const int t = blockIdx.x;                    // 0..TOK-1
  const int tid = threadIdx.x;
  const int d = tid & 31, g = tid >> 5;        // g 0..7
  const float c = cosp[t * 64 + d];
  const float s = sinp[t * 64 + d];
  bf16* row = qkv + (size_t)t * QKVN;
#pragma unroll
  for (int i = 0; i < 4; ++i) {
    bf16* p = row + (g + i * 8) * 64 + d;      // q heads
    float x1 = (float)p[0], x2 = (float)p[32];
    p[0]  = (bf16)(x1 * c - x2 * s);
    p[32] = (bf16)(x2 * c + x1 * s);
  }
  bf16* p = row + 2048 + g * 64 + d;           // k head
  float x1 = (float)p[0], x2 = (float)p[32];
  p[0]  = (bf16)(x1 * c - x2 * s);
  p[32] = (bf16)(x2 * c + x1 * s);
}

// ---------------- transpose V: qkv v-cols -> vT[(b*8+kv)][64][2048] ----------
__global__ __launch_bounds__(256) void transpose_v(const bf16* __restrict__ v,  // qkv + 2560
                                                   bf16* __restrict__ vT) {
  __shared__ __align__(16) bf16 t[64][72];
  const int bkv = blockIdx.y;
  const int b = bkv >> 3, kv = bkv & 7;
  const int s0 = blockIdx.x * 64;
  const int tid = threadIdx.x;
  const int r = tid >> 3, c = (tid & 7) * 8;
#pragma unroll
  for (int p = 0; p < 2; ++p) {
    int rr = r + p * 32;
    *(bf16x8*)&t[rr][c] = *(const bf16x8*)&v[(size_t)(b * S_ + s0 + rr) * QKVN + kv * 64 + c];
  }
  __syncthreads();
#pragma unroll
  for (int p = 0; p < 2; ++p) {
    int d = r + p * 32;
    bf16x8 o;
#pragma unroll
    for (int j = 0; j < 8; ++j) o[j] = t[c + j][d];
    *(bf16x8*)&vT[((size_t)bkv * 64 + d) * S_ + s0 + c] = o;
  }
}

// ---------------- fused causal attention (stripe-paired, 4 waves) ----------------
// block = (qt, bh): stripes LO = qt*64 and HI = (31-qt)*64 of one (b,h).
// wave w owns rows [w*16, w*16+16) in BOTH stripes; constant 33 tile-computes.
// SWAPPED QK^T: acc = mfma(K_frag, Q_frag) -> lane holds P[q=fr][k=nn*16+fg*4+r]
// (4 consecutive cols per acc reg) -> P written as f32x4, plain cached stores.
__global__ __launch_bounds__(256, 4) void attn_kernel(const bf16* __restrict__ qkv, // (TOK, 3072)
                                                      const bf16* __restrict__ vT,  // (16,64,2048)
                                                      float* __restrict__ attnw,    // (64, S, S)
                                                      bf16* __restrict__ attn_out)  // (TOK, 2048)
{
  __shared__ __align__(16) bf16 Ks[64][72];
  __shared__ __align__(16) bf16 Vs[64][72];
  __shared__ __align__(16) bf16 Ps[4][16][72];

  const int tid  = threadIdx.x;
  const int wave = tid >> 6, lane = tid & 63;
  const int qt = blockIdx.x;                   // 0..15
  const int bh = blockIdx.y;                   // 0..63
  const int b = bh >> 5, h = bh & 31, kv = h >> 2;
  const int qLo = qt * 64;                     // LO stripe base row
  const int qHi = (31 - qt) * 64;              // HI stripe base row
  const int NT  = 32 - qt;                     // K/V tiles staged (HI needs all)
  const int fr = lane & 15, fg = lane >> 4;
  const int rw = wave * 16;                    // wave's row base within stripe
  const int rt = rw + fg * 4;                  // attn_out row group
  const int thr = rw + fr;                     // lane's q-row within stripe (diag threshold)

  // Q fragments for both stripes (K=64 -> 2 chunks of 32); used as MFMA B-operand.
  bf16x8 aqL[2], aqH[2];
  {
    const bf16* qp = qkv + (size_t)(b * S_ + qLo + rw + fr) * QKVN + h * 64 + fg * 8;
    aqL[0] = *(const bf16x8*)qp;  aqL[1] = *(const bf16x8*)(qp + 32);
    qp = qkv + (size_t)(b * S_ + qHi + rw + fr) * QKVN + h * 64 + fg * 8;
    aqH[0] = *(const bf16x8*)qp;  aqH[1] = *(const bf16x8*)(qp + 32);
  }

  // staging geometry: 256 threads, 64 rows x 64 cols bf16 per tile
  const int lr = tid >> 2;                     // 0..63
  const int lc = (tid & 3) * 16;               // 0,16,32,48
  const bf16* kbase = qkv + (size_t)(b * S_) * QKVN + 2048 + kv * 64;
  const bf16* vbase = vT + (size_t)(b * NKV_ + kv) * 64 * S_;
  const bf16* kst = kbase + (size_t)lr * QKVN + lc;   // + jt*64*QKVN
  const bf16* vst = vbase + (size_t)lr * S_ + lc;     // + jt*64

  // ---------- pass 1: rowsums of exp(logit), swapped layout ----------
  float rsL = 0.f, rsH = 0.f;                  // scalar: lane owns q-row fr
  {
    bf16x8 kr0 = *(const bf16x8*)(kst);        // prefetch tile 0
    bf16x8 kr1 = *(const bf16x8*)(kst + 8);
    for (int jt = 0; jt < NT; ++jt) {
      __syncthreads();                          // all waves done with prev tile
      *(bf16x8*)&Ks[lr][lc]     = kr0;
      *(bf16x8*)&Ks[lr][lc + 8] = kr1;
      __syncthreads();
      if (jt + 1 < NT) {                        // prefetch next (block-uniform)
        const bf16* p = kst + (size_t)(jt + 1) * 64 * QKVN;
        kr0 = *(const bf16x8*)(p);
        kr1 = *(const bf16x8*)(p + 8);
      }
      // HI stripe (always active)
      {
        f32x4 acc[4] = {};
#pragma unroll
        for (int nn = 0; nn < 4; ++nn) {
          bf16x8 bk0 = *(const bf16x8*)&Ks[nn*16 + fr][fg*8];
          bf16x8 bk1 = *(const bf16x8*)&Ks[nn*16 + fr][32 + fg*8];
          acc[nn] = __builtin_amdgcn_mfma_f32_16x16x32_bf16(bk0, aqH[0], acc[nn], 0, 0, 0);
          acc[nn] = __builtin_amdgcn_mfma_f32_16x16x32_bf16(bk1, aqH[1], acc[nn], 0, 0, 0);
        }
        if (jt < NT - 1) {                      // fully unmasked
#pragma unroll
          for (int nn = 0; nn < 4; ++nn)
#pragma unroll
            for (int r = 0; r < 4; ++r) rsH += __expf(acc[nn][r] * 0.125f);
        } else {                                // HI diagonal tile: k <= q
#pragma unroll
          for (int nn = 0; nn < 4; ++nn)
#pragma unroll
            for (int r = 0; r < 4; ++r)
              if (nn * 16 + fg * 4 + r <= thr) rsH += __expf(acc[nn][r] * 0.125f);
        }
      }
      // LO stripe (active for jt <= qt; block-uniform)
      if (jt <= qt) {
        f32x4 acc[4] = {};
#pragma unroll
        for (int nn = 0; nn < 4; ++nn) {
          bf16x8 bk0 = *(const bf16x8*)&Ks[nn*16 + fr][fg*8];
          bf16x8 bk1 = *(const bf16x8*)&Ks[nn*16 + fr][32 + fg*8];
          acc[nn] = __builtin_amdgcn_mfma_f32_16x16x32_bf16(bk0, aqL[0], acc[nn], 0, 0, 0);
          acc[nn] = __builtin_amdgcn_mfma_f32_16x16x32_bf16(bk1, aqL[1], acc[nn], 0, 0, 0);
        }
        if (jt < qt) {
#pragma unroll
          for (int nn = 0; nn < 4; ++nn)
#pragma unroll
            for (int r = 0; r < 4; ++r) rsL += __expf(acc[nn][r] * 0.125f);
        } else {                                // LO diagonal tile
#pragma unroll
          for (int nn = 0; nn < 4; ++nn)
#pragma unroll
            for (int r = 0; r < 4; ++r)
              if (nn * 16 + fg * 4 + r <= thr) rsL += __expf(acc[nn][r] * 0.125f);
        }
      }
    }
  }
  // reduce across the 4 fg lane-groups (k-partitions), then invert
  {
    float v = rsL;
    v += __shfl_xor(v, 16); v += __shfl_xor(v, 32);
    rsL = 1.0f / v;
    v = rsH;
    v += __shfl_xor(v, 16); v += __shfl_xor(v, 32);
    rsH = 1.0f / v;
  }

  // ---------- zero-fill masked regions (write-free window of pass 1) ----------
  {
    f32x4 z4 = {0.f, 0.f, 0.f, 0.f};
    const int zLo = (qt + 1) * 64;              // LO rows: cols [zLo, S)
    for (int rr = 0; rr < 16; ++rr) {
      size_t base = ((size_t)bh * S_ + qLo + rw + rr) * S_;
      for (int c = zLo + lane * 4; c < S_; c += 256)
        __builtin_nontemporal_store(z4, (f32x4*)&attnw[base + c]);
    }
    const int zHi = NT * 64;                    // HI rows: cols [zHi, S)
    for (int rr = 0; rr < 16; ++rr) {
      size_t base = ((size_t)bh * S_ + qHi + rw + rr) * S_;
      for (int c = zHi + lane * 4; c < S_; c += 256)
        __builtin_nontemporal_store(z4, (f32x4*)&attnw[base + c]);
    }
  }

  // ---------- pass 2: recompute (swapped), write P f32x4, accumulate O ----------
  f32x4 oL[4] = {}, oH[4] = {};
  {
    float* awpL = attnw + ((size_t)bh * S_ + qLo + rw + fr) * S_;   // lane's LO row
    float* awpH = attnw + ((size_t)bh * S_ + qHi + rw + fr) * S_;   // lane's HI row
    const int cb = fg * 4;                      // lane's 4-col base within 16-window
    bf16x8 kr0 = *(const bf16x8*)(kst);        // prefetch tile 0
    bf16x8 kr1 = *(const bf16x8*)(kst + 8);
    bf16x8 vr0 = *(const bf16x8*)(vst);
    bf16x8 vr1 = *(const bf16x8*)(vst + 8);
    for (int jt = 0; jt < NT; ++jt) {
      const int j0 = jt * 64;
      __syncthreads();
      *(bf16x8*)&Ks[lr][lc]     = kr0;
      *(bf16x8*)&Ks[lr][lc + 8] = kr1;
      *(bf16x8*)&Vs[lr][lc]     = vr0;
      *(bf16x8*)&Vs[lr][lc + 8] = vr1;
      __syncthreads();
      if (jt + 1 < NT) {                        // prefetch next (block-uniform)
        const bf16* p = kst + (size_t)(jt + 1) * 64 * QKVN;
        kr0 = *(const bf16x8*)(p);
        kr1 = *(const bf16x8*)(p + 8);
        p = vst + (size_t)(jt + 1) * 64;
        vr0 = *(const bf16x8*)(p);
        vr1 = *(const bf16x8*)(p + 8);
      }
      // ---- HI stripe (always) ----
      {
        f32x4 acc[4] = {};
#pragma unroll
        for (int nn = 0; nn < 4; ++nn) {
          bf16x8 bk0 = *(const bf16x8*)&Ks[nn*16 + fr][fg*8];
          bf16x8 bk1 = *(const bf16x8*)&Ks[nn*16 + fr][32 + fg*8];
          acc[nn] = __builtin_amdgcn_mfma_f32_16x16x32_bf16(bk0, aqH[0], acc[nn], 0, 0, 0);
          acc[nn] = __builtin_amdgcn_mfma_f32_16x16x32_bf16(bk1, aqH[1], acc[nn], 0, 0, 0);
        }
        const bool diag = (jt == NT - 1);
#pragma unroll
        for (int nn = 0; nn < 4; ++nn) {
          f32x4 pv;
#pragma unroll
          for (int r = 0; r < 4; ++r) {
            float e = __expf(acc[nn][r] * 0.125f) * rsH;
            pv[r] = (diag && (nn * 16 + cb + r > thr)) ? 0.f : e;
            Ps[wave][fr][nn * 16 + cb + r] = (bf16)pv[r];
          }
          *(f32x4*)&awpH[j0 + nn * 16 + cb] = pv;   // plain cached store
        }
        bf16x8 pa0 = *(const bf16x8*)&Ps[wave][fr][fg * 8];
        bf16x8 pa1 = *(const bf16x8*)&Ps[wave][fr][32 + fg * 8];
#pragma unroll
        for (int nn = 0; nn < 4; ++nn) {
          bf16x8 bv0 = *(const bf16x8*)&Vs[nn*16 + fr][fg*8];
          bf16x8 bv1 = *(const bf16x8*)&Vs[nn*16 + fr][32 + fg*8];
          oH[nn] = __builtin_amdgcn_mfma_f32_16x16x32_bf16(pa0, bv0, oH[nn], 0, 0, 0);
          oH[nn] = __builtin_amdgcn_mfma_f32_16x16x32_bf16(pa1, bv1, oH[nn], 0, 0, 0);
        }
      }
      // ---- LO stripe (jt <= qt; block-uniform) ----
      if (jt <= qt) {
        f32x4 acc[4] = {};
#pragma unroll
        for (int nn = 0; nn < 4; ++nn) {
          bf16x8 bk0 = *(const bf16x8*)&Ks[nn*16 + fr][fg*8];
          bf16x8 bk1 = *(const bf16x8*)&Ks[nn*16 + fr][32 + fg*8];
          acc[nn] = __builtin_amdgcn_mfma_f32_16x16x32_bf16(bk0, aqL[0], acc[nn], 0, 0, 0);
          acc[nn] = __builtin_amdgcn_mfma_f32_16x16x32_bf16(bk1, aqL[1], acc[nn], 0, 0, 0);
        }
        const bool diag = (jt == qt);
#pragma unroll
        for (int nn = 0; nn < 4; ++nn) {
          f32x4 pv;
#pragma unroll
          for (int r = 0; r < 4; ++r) {
            float e = __expf(acc[nn][r] * 0.125f) * rsL;
            pv[r] = (diag && (nn * 16 + cb + r > thr)) ? 0.f : e;
            Ps[wave][fr][nn * 16 + cb + r] = (bf16)pv[r];
          }
          *(f32x4*)&awpL[j0 + nn * 16 + cb] = pv;   // plain cached store
        }
        bf16x8 pa0 = *(const bf16x8*)&Ps[wave][fr][fg * 8];
        bf16x8 pa1 = *(const bf16x8*)&Ps[wave][fr][32 + fg * 8];
#pragma unroll
        for (int nn = 0; nn < 4; ++nn) {
          bf16x8 bv0 = *(const bf16x8*)&Vs[nn*16 + fr][fg*8];
          bf16x8 bv1 = *(const bf16x8*)&Vs[nn*16 + fr][32 + fg*8];
          oL[nn] = __builtin_amdgcn_mfma_f32_16x16x32_bf16(pa0, bv0, oL[nn], 0, 0, 0);
          oL[nn] = __builtin_amdgcn_mfma_f32_16x16x32_bf16(pa1, bv1, oL[nn], 0, 0, 0);
        }
      }
    }
  }

  // attn_out (bf16) for both stripes (PV D-layout: row q = rt+r, col d = nn*16+fr)
#pragma unroll
  for (int nn = 0; nn < 4; ++nn)
#pragma unroll
    for (int r = 0; r < 4; ++r) {
      int rowL = qLo + rt + r;
      int rowH = qHi + rt + r;
      attn_out[(size_t)(b * S_ + rowL) * (NH_*HD_) + h * 64 + nn * 16 + fr] = (bf16)oL[nn][r];
      attn_out[(size_t)(b * S_ + rowH) * (NH_*HD_) + h * 64 + nn * 16 + fr] = (bf16)oH[nn][r];
    }
}

// ---------------------------------------------------------------------------
extern "C" void kernel_launch(void* const* d_in, const int* in_sizes, int n_in,
                              void* d_out, int out_size, void* d_ws, size_t ws_size,
                              hipStream_t stream) {
  const float* hs   = (const float*)d_in[0];
  const float* cosp = (const float*)d_in[1];
  const float* sinp = (const float*)d_in[2];
  // d_in[3] = attention_mask (causal; applied analytically)
  const float* Wq = (const float*)d_in[4];
  const float* Wk = (const float*)d_in[5];
  const float* Wv = (const float*)d_in[6];
  const float* Wo = (const float*)d_in[7];

  char* ws = (char*)d_ws;
  bf16* hs_b   = (bf16*)(ws);                   // 16 MB
  bf16* qkv_b  = (bf16*)(ws + (16u << 20));     // 24 MB (TOK x 3072)
  bf16* vT_b   = (bf16*)(ws + (40u << 20));     // 4 MB
  bf16* ao_b   = (bf16*)(ws + (44u << 20));     // 16 MB
  bf16* Wqkv_b = (bf16*)(ws + (60u << 20));     // 12 MB (3072 x 2048)
  bf16* Wo_b   = (bf16*)(ws + (72u << 20));     // 8 MB

  float* outp  = (float*)d_out;
  float* attnw = outp + (size_t)TOK_ * HID_;    // + 8388608

  // casts to bf16
  cast_f32_bf16<<<(TOK_*HID_/4 + 255)/256, 256, 0, stream>>>(hs, hs_b, TOK_*HID_/4);
  cast_wqkv<<<(1572864 + 255)/256, 256, 0, stream>>>(Wq, Wk, Wv, Wqkv_b);
  cast_f32_bf16<<<(HID_*NH_*HD_/4 + 255)/256, 256, 0, stream>>>(Wo, Wo_b, HID_*NH_*HD_/4);

  // fused QKV projection: (TOK,2048) @ (3072,2048)^T -> (TOK,3072)
  gemm_bt<false><<<dim3(QKVN/128, TOK_/128), 256, 0, stream>>>(hs_b, Wqkv_b, qkv_b, TOK_, QKVN, HID_);

  // RoPE (in place, one block per token)
  rope_fused<<<TOK_, 256, 0, stream>>>(qkv_b, cosp, sinp);

  // V transpose for PV B-operand contiguity
  transpose_v<<<dim3(S_/64, B_*NKV_), 256, 0, stream>>>(qkv_b + 2560, vT_b);

  // fused attention (stripe-paired; writes attn_weights f32 + attn_out bf16)
  attn_kernel<<<dim3(S_/128, B_*NH_), 256, 0, stream>>>(qkv_b, vT_b, attnw, ao_b);

  // output projection (f32 out)
  gemm_bt<true><<<dim3(HID_/128, TOK_/128), 256, 0, stream>>>(ao_b, Wo_b, outp, TOK_, HID_, HID_);
}

// Round 8
// 433.341 us; speedup vs baseline: 1.2166x; 1.0292x over previous
//
#include <hip/hip_runtime.h>
#include <hip/hip_bf16.h>

// ---------------------------------------------------------------------------
// SmallthinkerAttention: hs->QKV proj -> RoPE -> causal attn (writes P) -> out proj
// B=2 S=2048 HID=2048 NH=32 NKV=8 HD=64
// d_out = [out (2*2048*2048 f32), attn_weights (2*32*2048*2048 f32)]
// R8: write-pipe balancing in attn: zero-fill issued BEFORE pass 1 (drains
//     during the write-idle sums phase), pass-1 K double-buffered (1 barrier
//     per tile), Ps LDS writes packed to bf16x4. Everything else = R7.
// ---------------------------------------------------------------------------

typedef __bf16 bf16;
typedef bf16 bf16x8 __attribute__((ext_vector_type(8)));
typedef bf16 bf16x4 __attribute__((ext_vector_type(4)));
typedef float f32x4 __attribute__((ext_vector_type(4)));

#define B_   2
#define S_   2048
#define HID_ 2048
#define NH_  32
#define NKV_ 8
#define HD_  64
#define TOK_ (B_*S_)          // 4096
#define QKVN 3072             // fused QKV output cols: 2048 q | 512 k | 512 v

// async global->LDS, 16B per lane, LDS dest = wave-uniform base + lane*16
__device__ __forceinline__ void gl_lds16(const bf16* g, bf16* l) {
  __builtin_amdgcn_global_load_lds(
      (const __attribute__((address_space(1))) unsigned int*)(g),
      (__attribute__((address_space(3))) unsigned int*)(l), 16, 0, 0);
}

// ---------------- cast f32 -> bf16 (vectorized) ----------------
__global__ __launch_bounds__(256) void cast_f32_bf16(const float* __restrict__ in,
                                                     bf16* __restrict__ out, int n4) {
  int i = blockIdx.x * 256 + threadIdx.x;
  if (i >= n4) return;
  f32x4 v = ((const f32x4*)in)[i];
  bf16x4 o;
  o[0] = (bf16)v[0]; o[1] = (bf16)v[1]; o[2] = (bf16)v[2]; o[3] = (bf16)v[3];
  ((bf16x4*)out)[i] = o;
}

// fused Wq|Wk|Wv cast into contiguous Wqkv (rows: 2048 q | 512 k | 512 v)
__global__ __launch_bounds__(256) void cast_wqkv(const float* __restrict__ wq,
                                                 const float* __restrict__ wk,
                                                 const float* __restrict__ wv,
                                                 bf16* __restrict__ dst) {
  int i = blockIdx.x * 256 + threadIdx.x;      // 0 .. 1572863 (x4 units)
  const float* src; int off;
  if (i < 1048576)      { src = wq; off = i; }
  else if (i < 1310720) { src = wk; off = i - 1048576; }
  else                  { src = wv; off = i - 1310720; }
  f32x4 v = ((const f32x4*)src)[off];
  bf16x4 o;
  o[0] = (bf16)v[0]; o[1] = (bf16)v[1]; o[2] = (bf16)v[2]; o[3] = (bf16)v[3];
  ((bf16x4*)dst)[i] = o;
}

// ---------------- GEMM: C[M,N] = A[M,K] @ B[N,K]^T  (bf16 in, bf16/f32 out) ----
// m97 structure + T1 XCD swizzle. Linear LDS (required by global_load_lds).
template<bool OUT_F32>
__global__ __launch_bounds__(256) void gemm_bt(const bf16* __restrict__ A,
                                               const bf16* __restrict__ Bm,
                                               void* __restrict__ Cout,
                                               int M, int N, int K) {
  __shared__ __align__(16) bf16 As[128 * 32];
  __shared__ __align__(16) bf16 Bs[128 * 32];
  const int tid  = threadIdx.x;
  const int wave = tid >> 6, lane = tid & 63;

  // T1 XCD-aware swizzle (nwg % 8 == 0 for all our launches)
  const int nwg = (int)(gridDim.x * gridDim.y);
  const int bid = (int)(blockIdx.y * gridDim.x + blockIdx.x);
  const int swz = (bid & 7) * (nwg >> 3) + (bid >> 3);
  const int bx = swz % (int)gridDim.x, by = swz / (int)gridDim.x;

  const int bm = by * 128, bn = bx * 128;
  const int wm = (wave >> 1) * 64, wn = (wave & 1) * 64;
  const int fr = lane & 15, fg = lane >> 4;

  const int r0   = wave * 32 + (lane >> 2);
  const int scol = (lane & 3) * 8;
  const bf16* ga0 = A  + (size_t)(bm + r0) * K + scol;
  const bf16* ga1 = ga0 + (size_t)16 * K;
  const bf16* gb0 = Bm + (size_t)(bn + r0) * K + scol;
  const bf16* gb1 = gb0 + (size_t)16 * K;
  bf16* lA0 = As + (wave * 32) * 32;
  bf16* lA1 = lA0 + 16 * 32;
  bf16* lB0 = Bs + (wave * 32) * 32;
  bf16* lB1 = lB0 + 16 * 32;

  f32x4 acc[4][4] = {};

  for (int k0 = 0; k0 < K; k0 += 32) {
    gl_lds16(ga0 + k0, lA0);
    gl_lds16(ga1 + k0, lA1);
    gl_lds16(gb0 + k0, lB0);
    gl_lds16(gb1 + k0, lB1);
    __syncthreads();
    bf16x8 af[4], bfv[4];
#pragma unroll
    for (int i = 0; i < 4; ++i) {
      af[i]  = *(const bf16x8*)&As[(wm + i * 16 + fr) * 32 + fg * 8];
      bfv[i] = *(const bf16x8*)&Bs[(wn + i * 16 + fr) * 32 + fg * 8];
    }
#pragma unroll
    for (int i = 0; i < 4; ++i)
#pragma unroll
      for (int j = 0; j < 4; ++j)
        acc[i][j] = __builtin_amdgcn_mfma_f32_16x16x32_bf16(af[i], bfv[j], acc[i][j], 0, 0, 0);
    __syncthreads();
  }

#pragma unroll
  for (int i = 0; i < 4; ++i)
#pragma unroll
    for (int j = 0; j < 4; ++j)
#pragma unroll
      for (int r = 0; r < 4; ++r) {
        int row = bm + wm + i * 16 + fg * 4 + r;
        int col = bn + wn + j * 16 + fr;
        float v = acc[i][j][r];
        if (OUT_F32) ((float*)Cout)[(size_t)row * N + col] = v;
        else         ((bf16*)Cout)[(size_t)row * N + col] = (bf16)v;
      }
}

// ---------------- RoPE: one block per token, q (32 heads) + k (8 heads) ------
__global__ __launch_bounds__(256) void rope_fused(bf16* __restrict__ qkv,
                                                  const float* __restrict__ cosp,
                                                  const float* __restrict__ sinp) {
  const int t = blockIdx.x;                    // 0..TOK-1
  const int tid = threadIdx.x;
  const int d = tid & 31, g = tid >> 5;        // g 0..7
  const float c = cosp[t * 64 + d];
  const float s = sinp[t * 64 + d];
  bf16* row = qkv + (size_t)t * QKVN;
#pragma unroll
  for (int i = 0; i < 4; ++i) {
    bf16* p = row + (g + i * 8) * 64 + d;      // q heads
    float x1 = (float)p[0], x2 = (float)p[32];
    p[0]  = (bf16)(x1 * c - x2 * s);
    p[32] = (bf16)(x2 * c + x1 * s);
  }
  bf16* p = row + 2048 + g * 64 + d;           // k head
  float x1 = (float)p[0], x2 = (float)p[32];
  p[0]  = (bf16)(x1 * c - x2 * s);
  p[32] = (bf16)(x2 * c + x1 * s);
}

// ---------------- transpose V: qkv v-cols -> vT[(b*8+kv)][64][2048] ----------
__global__ __launch_bounds__(256) void transpose_v(const bf16* __restrict__ v,  // qkv + 2560
                                                   bf16* __restrict__ vT) {
  __shared__ __align__(16) bf16 t[64][72];
  const int bkv = blockIdx.y;
  const int b = bkv >> 3, kv = bkv & 7;
  const int s0 = blockIdx.x * 64;
  const int tid = threadIdx.x;
  const int r = tid >> 3, c = (tid & 7) * 8;
#pragma unroll
  for (int p = 0; p < 2; ++p) {
    int rr = r + p * 32;
    *(bf16x8*)&t[rr][c] = *(const bf16x8*)&v[(size_t)(b * S_ + s0 + rr) * QKVN + kv * 64 + c];
  }
  __syncthreads();
#pragma unroll
  for (int p = 0; p < 2; ++p) {
    int d = r + p * 32;
    bf16x8 o;
#pragma unroll
    for (int j = 0; j < 8; ++j) o[j] = t[c + j][d];
    *(bf16x8*)&vT[((size_t)bkv * 64 + d) * S_ + s0 + c] = o;
  }
}

// ---------------- fused causal attention (stripe-paired, 4 waves) ----------------
// block = (qt, bh): stripes LO = qt*64 and HI = (31-qt)*64 of one (b,h).
// wave w owns rows [w*16, w*16+16) in BOTH stripes; constant 33 tile-computes.
// SWAPPED QK^T: acc = mfma(K_frag, Q_frag) -> lane holds P[q=fr][k=nn*16+fg*4+r].
// Order: zero-fill (NT stores drain during sums) -> pass1 (K dbuf, 1 barrier)
// -> pass2 (recompute, f32x4 cached P stores, PV accumulate).
__global__ __launch_bounds__(256, 4) void attn_kernel(const bf16* __restrict__ qkv, // (TOK, 3072)
                                                      const bf16* __restrict__ vT,  // (16,64,2048)
                                                      float* __restrict__ attnw,    // (64, S, S)
                                                      bf16* __restrict__ attn_out)  // (TOK, 2048)
{
  __shared__ __align__(16) bf16 Ks2[2][64][72];
  __shared__ __align__(16) bf16 Vs[64][72];
  __shared__ __align__(16) bf16 Ps[4][16][72];

  const int tid  = threadIdx.x;
  const int wave = tid >> 6, lane = tid & 63;
  const int qt = blockIdx.x;                   // 0..15
  const int bh = blockIdx.y;                   // 0..63
  const int b = bh >> 5, h = bh & 31, kv = h >> 2;
  const int qLo = qt * 64;                     // LO stripe base row
  const int qHi = (31 - qt) * 64;              // HI stripe base row
  const int NT  = 32 - qt;                     // K/V tiles staged (HI needs all)
  const int fr = lane & 15, fg = lane >> 4;
  const int rw = wave * 16;                    // wave's row base within stripe
  const int rt = rw + fg * 4;                  // attn_out row group
  const int thr = rw + fr;                     // lane's q-row within stripe (diag threshold)

  // Q fragments for both stripes (K=64 -> 2 chunks of 32); used as MFMA B-operand.
  bf16x8 aqL[2], aqH[2];
  {
    const bf16* qp = qkv + (size_t)(b * S_ + qLo + rw + fr) * QKVN + h * 64 + fg * 8;
    aqL[0] = *(const bf16x8*)qp;  aqL[1] = *(const bf16x8*)(qp + 32);
    qp = qkv + (size_t)(b * S_ + qHi + rw + fr) * QKVN + h * 64 + fg * 8;
    aqH[0] = *(const bf16x8*)qp;  aqH[1] = *(const bf16x8*)(qp + 32);
  }

  // staging geometry: 256 threads, 64 rows x 64 cols bf16 per tile
  const int lr = tid >> 2;                     // 0..63
  const int lc = (tid & 3) * 16;               // 0,16,32,48
  const bf16* kbase = qkv + (size_t)(b * S_) * QKVN + 2048 + kv * 64;
  const bf16* vbase = vT + (size_t)(b * NKV_ + kv) * 64 * S_;
  const bf16* kst = kbase + (size_t)lr * QKVN + lc;   // + jt*64*QKVN
  const bf16* vst = vbase + (size_t)lr * S_ + lc;     // + jt*64

  // ---------- zero-fill masked regions FIRST (drains during pass-1 compute) ----------
  {
    f32x4 z4 = {0.f, 0.f, 0.f, 0.f};
    const int zLo = (qt + 1) * 64;              // LO rows: cols [zLo, S)
    for (int rr = 0; rr < 16; ++rr) {
      size_t base = ((size_t)bh * S_ + qLo + rw + rr) * S_;
      for (int c = zLo + lane * 4; c < S_; c += 256)
        __builtin_nontemporal_store(z4, (f32x4*)&attnw[base + c]);
    }
    const int zHi = NT * 64;                    // HI rows: cols [zHi, S)
    for (int rr = 0; rr < 16; ++rr) {
      size_t base = ((size_t)bh * S_ + qHi + rw + rr) * S_;
      for (int c = zHi + lane * 4; c < S_; c += 256)
        __builtin_nontemporal_store(z4, (f32x4*)&attnw[base + c]);
    }
  }

  // ---------- pass 1: rowsums of exp(logit), K double-buffered ----------
  float rsL = 0.f, rsH = 0.f;                  // scalar: lane owns q-row fr
  {
    bf16x8 kr0 = *(const bf16x8*)(kst);        // tile 0
    bf16x8 kr1 = *(const bf16x8*)(kst + 8);
    *(bf16x8*)&Ks2[0][lr][lc]     = kr0;
    *(bf16x8*)&Ks2[0][lr][lc + 8] = kr1;
    __syncthreads();
    for (int jt = 0; jt < NT; ++jt) {
      const int cur = jt & 1;
      if (jt + 1 < NT) {                        // prefetch next tile to regs
        const bf16* p = kst + (size_t)(jt + 1) * 64 * QKVN;
        kr0 = *(const bf16x8*)(p);
        kr1 = *(const bf16x8*)(p + 8);
      }
      // HI stripe (always active)
      {
        f32x4 acc[4] = {};
#pragma unroll
        for (int nn = 0; nn < 4; ++nn) {
          bf16x8 bk0 = *(const bf16x8*)&Ks2[cur][nn*16 + fr][fg*8];
          bf16x8 bk1 = *(const bf16x8*)&Ks2[cur][nn*16 + fr][32 + fg*8];
          acc[nn] = __builtin_amdgcn_mfma_f32_16x16x32_bf16(bk0, aqH[0], acc[nn], 0, 0, 0);
          acc[nn] = __builtin_amdgcn_mfma_f32_16x16x32_bf16(bk1, aqH[1], acc[nn], 0, 0, 0);
        }
        if (jt < NT - 1) {                      // fully unmasked
#pragma unroll
          for (int nn = 0; nn < 4; ++nn)
#pragma unroll
            for (int r = 0; r < 4; ++r) rsH += __expf(acc[nn][r] * 0.125f);
        } else {                                // HI diagonal tile: k <= q
#pragma unroll
          for (int nn = 0; nn < 4; ++nn)
#pragma unroll
            for (int r = 0; r < 4; ++r)
              if (nn * 16 + fg * 4 + r <= thr) rsH += __expf(acc[nn][r] * 0.125f);
        }
      }
      // LO stripe (active for jt <= qt; block-uniform)
      if (jt <= qt) {
        f32x4 acc[4] = {};
#pragma unroll
        for (int nn = 0; nn < 4; ++nn) {
          bf16x8 bk0 = *(const bf16x8*)&Ks2[cur][nn*16 + fr][fg*8];
          bf16x8 bk1 = *(const bf16x8*)&Ks2[cur][nn*16 + fr][32 + fg*8];
          acc[nn] = __builtin_amdgcn_mfma_f32_16x16x32_bf16(bk0, aqL[0], acc[nn], 0, 0, 0);
          acc[nn] = __builtin_amdgcn_mfma_f32_16x16x32_bf16(bk1, aqL[1], acc[nn], 0, 0, 0);
        }
        if (jt < qt) {
#pragma unroll
          for (int nn = 0; nn < 4; ++nn)
#pragma unroll
            for (int r = 0; r < 4; ++r) rsL += __expf(acc[nn][r] * 0.125f);
        } else {                                // LO diagonal tile
#pragma unroll
          for (int nn = 0; nn < 4; ++nn)
#pragma unroll
            for (int r = 0; r < 4; ++r)
              if (nn * 16 + fg * 4 + r <= thr) rsL += __expf(acc[nn][r] * 0.125f);
        }
      }
      if (jt + 1 < NT) {                        // stage next tile, ONE barrier
        *(bf16x8*)&Ks2[cur ^ 1][lr][lc]     = kr0;
        *(bf16x8*)&Ks2[cur ^ 1][lr][lc + 8] = kr1;
        __syncthreads();
      }
    }
  }
  // reduce across the 4 fg lane-groups (k-partitions), then invert
  {
    float v = rsL;
    v += __shfl_xor(v, 16); v += __shfl_xor(v, 32);
    rsL = 1.0f / v;
    v = rsH;
    v += __shfl_xor(v, 16); v += __shfl_xor(v, 32);
    rsH = 1.0f / v;
  }

  // ---------- pass 2: recompute (swapped), write P f32x4, accumulate O ----------
  f32x4 oL[4] = {}, oH[4] = {};
  {
    float* awpL = attnw + ((size_t)bh * S_ + qLo + rw + fr) * S_;   // lane's LO row
    float* awpH = attnw + ((size_t)bh * S_ + qHi + rw + fr) * S_;   // lane's HI row
    const int cb = fg * 4;                      // lane's 4-col base within 16-window
    bf16x8 kr0 = *(const bf16x8*)(kst);        // prefetch tile 0
    bf16x8 kr1 = *(const bf16x8*)(kst + 8);
    bf16x8 vr0 = *(const bf16x8*)(vst);
    bf16x8 vr1 = *(const bf16x8*)(vst + 8);
    for (int jt = 0; jt < NT; ++jt) {
      const int j0 = jt * 64;
      __syncthreads();
      *(bf16x8*)&Ks2[0][lr][lc]     = kr0;
      *(bf16x8*)&Ks2[0][lr][lc + 8] = kr1;
      *(bf16x8*)&Vs[lr][lc]     = vr0;
      *(bf16x8*)&Vs[lr][lc + 8] = vr1;
      __syncthreads();
      if (jt + 1 < NT) {                        // prefetch next (block-uniform)
        const bf16* p = kst + (size_t)(jt + 1) * 64 * QKVN;
        kr0 = *(const bf16x8*)(p);
        kr1 = *(const bf16x8*)(p + 8);
        p = vst + (size_t)(jt + 1) * 64;
        vr0 = *(const bf16x8*)(p);
        vr1 = *(const bf16x8*)(p + 8);
      }
      // ---- HI stripe (always) ----
      {
        f32x4 acc[4] = {};
#pragma unroll
        for (int nn = 0; nn < 4; ++nn) {
          bf16x8 bk0 = *(const bf16x8*)&Ks2[0][nn*16 + fr][fg*8];
          bf16x8 bk1 = *(const bf16x8*)&Ks2[0][nn*16 + fr][32 + fg*8];
          acc[nn] = __builtin_amdgcn_mfma_f32_16x16x32_bf16(bk0, aqH[0], acc[nn], 0, 0, 0);
          acc[nn] = __builtin_amdgcn_mfma_f32_16x16x32_bf16(bk1, aqH[1], acc[nn], 0, 0, 0);
        }
        const bool diag = (jt == NT - 1);
#pragma unroll
        for (int nn = 0; nn < 4; ++nn) {
          f32x4 pv;
          bf16x4 pb;
#pragma unroll
          for (int r = 0; r < 4; ++r) {
            float e = __expf(acc[nn][r] * 0.125f) * rsH;
            pv[r] = (diag && (nn * 16 + cb + r > thr)) ? 0.f : e;
            pb[r] = (bf16)pv[r];
          }
          *(f32x4*)&awpH[j0 + nn * 16 + cb] = pv;   // plain cached store
          *(bf16x4*)&Ps[wave][fr][nn * 16 + cb] = pb;
        }
        bf16x8 pa0 = *(const bf16x8*)&Ps[wave][fr][fg * 8];
        bf16x8 pa1 = *(const bf16x8*)&Ps[wave][fr][32 + fg * 8];
#pragma unroll
        for (int nn = 0; nn < 4; ++nn) {
          bf16x8 bv0 = *(const bf16x8*)&Vs[nn*16 + fr][fg*8];
          bf16x8 bv1 = *(const bf16x8*)&Vs[nn*16 + fr][32 + fg*8];
          oH[nn] = __builtin_amdgcn_mfma_f32_16x16x32_bf16(pa0, bv0, oH[nn], 0, 0, 0);
          oH[nn] = __builtin_amdgcn_mfma_f32_16x16x32_bf16(pa1, bv1, oH[nn], 0, 0, 0);
        }
      }
      // ---- LO stripe (jt <= qt; block-uniform) ----
      if (jt <= qt) {
        f32x4 acc[4] = {};
#pragma unroll
        for (int nn = 0; nn < 4; ++nn) {
          bf16x8 bk0 = *(const bf16x8*)&Ks2[0][nn*16 + fr][fg*8];
          bf16x8 bk1 = *(const bf16x8*)&Ks2[0][nn*16 + fr][32 + fg*8];
          acc[nn] = __builtin_amdgcn_mfma_f32_16x16x32_bf16(bk0, aqL[0], acc[nn], 0, 0, 0);
          acc[nn] = __builtin_amdgcn_mfma_f32_16x16x32_bf16(bk1, aqL[1], acc[nn], 0, 0, 0);
        }
        const bool diag = (jt == qt);
#pragma unroll
        for (int nn = 0; nn < 4; ++nn) {
          f32x4 pv;
          bf16x4 pb;
#pragma unroll
          for (int r = 0; r < 4; ++r) {
            float e = __expf(acc[nn][r] * 0.125f) * rsL;
            pv[r] = (diag && (nn * 16 + cb + r > thr)) ? 0.f : e;
            pb[r] = (bf16)pv[r];
          }
          *(f32x4*)&awpL[j0 + nn * 16 + cb] = pv;   // plain cached store
          *(bf16x4*)&Ps[wave][fr][nn * 16 + cb] = pb;
        }
        bf16x8 pa0 = *(const bf16x8*)&Ps[wave][fr][fg * 8];
        bf16x8 pa1 = *(const bf16x8*)&Ps[wave][fr][32 + fg * 8];
#pragma unroll
        for (int nn = 0; nn < 4; ++nn) {
          bf16x8 bv0 = *(const bf16x8*)&Vs[nn*16 + fr][fg*8];
          bf16x8 bv1 = *(const bf16x8*)&Vs[nn*16 + fr][32 + fg*8];
          oL[nn] = __builtin_amdgcn_mfma_f32_16x16x32_bf16(pa0, bv0, oL[nn], 0, 0, 0);
          oL[nn] = __builtin_amdgcn_mfma_f32_16x16x32_bf16(pa1, bv1, oL[nn], 0, 0, 0);
        }
      }
    }
  }

  // attn_out (bf16) for both stripes (PV D-layout: row q = rt+r, col d = nn*16+fr)
#pragma unroll
  for (int nn = 0; nn < 4; ++nn)
#pragma unroll
    for (int r = 0; r < 4; ++r) {
      int rowL = qLo + rt + r;
      int rowH = qHi + rt + r;
      attn_out[(size_t)(b * S_ + rowL) * (NH_*HD_) + h * 64 + nn * 16 + fr] = (bf16)oL[nn][r];
      attn_out[(size_t)(b * S_ + rowH) * (NH_*HD_) + h * 64 + nn * 16 + fr] = (bf16)oH[nn][r];
    }
}

// ---------------------------------------------------------------------------
extern "C" void kernel_launch(void* const* d_in, const int* in_sizes, int n_in,
                              void* d_out, int out_size, void* d_ws, size_t ws_size,
                              hipStream_t stream) {
  const float* hs   = (const float*)d_in[0];
  const float* cosp = (const float*)d_in[1];
  const float* sinp = (const float*)d_in[2];
  // d_in[3] = attention_mask (causal; applied analytically)
  const float* Wq = (const float*)d_in[4];
  const float* Wk = (const float*)d_in[5];
  const float* Wv = (const float*)d_in[6];
  const float* Wo = (const float*)d_in[7];

  char* ws = (char*)d_ws;
  bf16* hs_b   = (bf16*)(ws);                   // 16 MB
  bf16* qkv_b  = (bf16*)(ws + (16u << 20));     // 24 MB (TOK x 3072)
  bf16* vT_b   = (bf16*)(ws + (40u << 20));     // 4 MB
  bf16* ao_b   = (bf16*)(ws + (44u << 20));     // 16 MB
  bf16* Wqkv_b = (bf16*)(ws + (60u << 20));     // 12 MB (3072 x 2048)
  bf16* Wo_b   = (bf16*)(ws + (72u << 20));     // 8 MB

  float* outp  = (float*)d_out;
  float* attnw = outp + (size_t)TOK_ * HID_;    // + 8388608

  // casts to bf16
  cast_f32_bf16<<<(TOK_*HID_/4 + 255)/256, 256, 0, stream>>>(hs, hs_b, TOK_*HID_/4);
  cast_wqkv<<<(1572864 + 255)/256, 256, 0, stream>>>(Wq, Wk, Wv, Wqkv_b);
  cast_f32_bf16<<<(HID_*NH_*HD_/4 + 255)/256, 256, 0, stream>>>(Wo, Wo_b, HID_*NH_*HD_/4);

  // fused QKV projection: (TOK,2048) @ (3072,2048)^T -> (TOK,3072)
  gemm_bt<false><<<dim3(QKVN/128, TOK_/128), 256, 0, stream>>>(hs_b, Wqkv_b, qkv_b, TOK_, QKVN, HID_);

  // RoPE (in place, one block per token)
  rope_fused<<<TOK_, 256, 0, stream>>>(qkv_b, cosp, sinp);

  // V transpose for PV B-operand contiguity
  transpose_v<<<dim3(S_/64, B_*NKV_), 256, 0, stream>>>(qkv_b + 2560, vT_b);

  // fused attention (stripe-paired; writes attn_weights f32 + attn_out bf16)
  attn_kernel<<<dim3(S_/128, B_*NH_), 256, 0, stream>>>(qkv_b, vT_b, attnw, ao_b);

  // output projection (f32 out)
  gemm_bt<true><<<dim3(HID_/128, TOK_/128), 256, 0, stream>>>(ao_b, Wo_b, outp, TOK_, HID_, HID_);
}

// Round 9
// 433.331 us; speedup vs baseline: 1.2166x; 1.0000x over previous
//
#include <hip/hip_runtime.h>
#include <hip/hip_bf16.h>

// ---------------------------------------------------------------------------
// SmallthinkerAttention: hs->QKV proj -> RoPE -> causal attn (writes P) -> out proj
// B=2 S=2048 HID=2048 NH=32 NKV=8 HD=64
// d_out = [out (2*2048*2048 f32), attn_weights (2*32*2048*2048 f32)]
// R9: attn barriers switched to raw s_barrier + lgkmcnt(0)-only waits.
//     __syncthreads()'s implicit vmcnt(0) drain was serializing the P/zero-fill
//     store stream against compute (attn = compute + writes, additive). With
//     counted-vmcnt semantics stores drain in background -> max(), not sum.
//     Barrier positions identical to R8; only drain semantics weakened.
// ---------------------------------------------------------------------------

typedef __bf16 bf16;
typedef bf16 bf16x8 __attribute__((ext_vector_type(8)));
typedef bf16 bf16x4 __attribute__((ext_vector_type(4)));
typedef float f32x4 __attribute__((ext_vector_type(4)));

#define B_   2
#define S_   2048
#define HID_ 2048
#define NH_  32
#define NKV_ 8
#define HD_  64
#define TOK_ (B_*S_)          // 4096
#define QKVN 3072             // fused QKV output cols: 2048 q | 512 k | 512 v

// barrier WITHOUT the implicit vmcnt(0) drain: LDS ops settled, stores keep draining
#define BAR_LGKM() do { asm volatile("s_waitcnt lgkmcnt(0)" ::: "memory"); \
                        __builtin_amdgcn_s_barrier(); } while (0)

// async global->LDS, 16B per lane, LDS dest = wave-uniform base + lane*16
__device__ __forceinline__ void gl_lds16(const bf16* g, bf16* l) {
  __builtin_amdgcn_global_load_lds(
      (const __attribute__((address_space(1))) unsigned int*)(g),
      (__attribute__((address_space(3))) unsigned int*)(l), 16, 0, 0);
}

// ---------------- cast f32 -> bf16 (vectorized) ----------------
__global__ __launch_bounds__(256) void cast_f32_bf16(const float* __restrict__ in,
                                                     bf16* __restrict__ out, int n4) {
  int i = blockIdx.x * 256 + threadIdx.x;
  if (i >= n4) return;
  f32x4 v = ((const f32x4*)in)[i];
  bf16x4 o;
  o[0] = (bf16)v[0]; o[1] = (bf16)v[1]; o[2] = (bf16)v[2]; o[3] = (bf16)v[3];
  ((bf16x4*)out)[i] = o;
}

// fused Wq|Wk|Wv cast into contiguous Wqkv (rows: 2048 q | 512 k | 512 v)
__global__ __launch_bounds__(256) void cast_wqkv(const float* __restrict__ wq,
                                                 const float* __restrict__ wk,
                                                 const float* __restrict__ wv,
                                                 bf16* __restrict__ dst) {
  int i = blockIdx.x * 256 + threadIdx.x;      // 0 .. 1572863 (x4 units)
  const float* src; int off;
  if (i < 1048576)      { src = wq; off = i; }
  else if (i < 1310720) { src = wk; off = i - 1048576; }
  else                  { src = wv; off = i - 1310720; }
  f32x4 v = ((const f32x4*)src)[off];
  bf16x4 o;
  o[0] = (bf16)v[0]; o[1] = (bf16)v[1]; o[2] = (bf16)v[2]; o[3] = (bf16)v[3];
  ((bf16x4*)dst)[i] = o;
}

// ---------------- GEMM: C[M,N] = A[M,K] @ B[N,K]^T  (bf16 in, bf16/f32 out) ----
// m97 structure + T1 XCD swizzle. Linear LDS (required by global_load_lds).
template<bool OUT_F32>
__global__ __launch_bounds__(256) void gemm_bt(const bf16* __restrict__ A,
                                               const bf16* __restrict__ Bm,
                                               void* __restrict__ Cout,
                                               int M, int N, int K) {
  __shared__ __align__(16) bf16 As[128 * 32];
  __shared__ __align__(16) bf16 Bs[128 * 32];
  const int tid  = threadIdx.x;
  const int wave = tid >> 6, lane = tid & 63;

  // T1 XCD-aware swizzle (nwg % 8 == 0 for all our launches)
  const int nwg = (int)(gridDim.x * gridDim.y);
  const int bid = (int)(blockIdx.y * gridDim.x + blockIdx.x);
  const int swz = (bid & 7) * (nwg >> 3) + (bid >> 3);
  const int bx = swz % (int)gridDim.x, by = swz / (int)gridDim.x;

  const int bm = by * 128, bn = bx * 128;
  const int wm = (wave >> 1) * 64, wn = (wave & 1) * 64;
  const int fr = lane & 15, fg = lane >> 4;

  const int r0   = wave * 32 + (lane >> 2);
  const int scol = (lane & 3) * 8;
  const bf16* ga0 = A  + (size_t)(bm + r0) * K + scol;
  const bf16* ga1 = ga0 + (size_t)16 * K;
  const bf16* gb0 = Bm + (size_t)(bn + r0) * K + scol;
  const bf16* gb1 = gb0 + (size_t)16 * K;
  bf16* lA0 = As + (wave * 32) * 32;
  bf16* lA1 = lA0 + 16 * 32;
  bf16* lB0 = Bs + (wave * 32) * 32;
  bf16* lB1 = lB0 + 16 * 32;

  f32x4 acc[4][4] = {};

  for (int k0 = 0; k0 < K; k0 += 32) {
    gl_lds16(ga0 + k0, lA0);
    gl_lds16(ga1 + k0, lA1);
    gl_lds16(gb0 + k0, lB0);
    gl_lds16(gb1 + k0, lB1);
    __syncthreads();
    bf16x8 af[4], bfv[4];
#pragma unroll
    for (int i = 0; i < 4; ++i) {
      af[i]  = *(const bf16x8*)&As[(wm + i * 16 + fr) * 32 + fg * 8];
      bfv[i] = *(const bf16x8*)&Bs[(wn + i * 16 + fr) * 32 + fg * 8];
    }
#pragma unroll
    for (int i = 0; i < 4; ++i)
#pragma unroll
      for (int j = 0; j < 4; ++j)
        acc[i][j] = __builtin_amdgcn_mfma_f32_16x16x32_bf16(af[i], bfv[j], acc[i][j], 0, 0, 0);
    __syncthreads();
  }

#pragma unroll
  for (int i = 0; i < 4; ++i)
#pragma unroll
    for (int j = 0; j < 4; ++j)
#pragma unroll
      for (int r = 0; r < 4; ++r) {
        int row = bm + wm + i * 16 + fg * 4 + r;
        int col = bn + wn + j * 16 + fr;
        float v = acc[i][j][r];
        if (OUT_F32) ((float*)Cout)[(size_t)row * N + col] = v;
        else         ((bf16*)Cout)[(size_t)row * N + col] = (bf16)v;
      }
}

// ---------------- RoPE: one block per token, q (32 heads) + k (8 heads) ------
__global__ __launch_bounds__(256) void rope_fused(bf16* __restrict__ qkv,
                                                  const float* __restrict__ cosp,
                                                  const float* __restrict__ sinp) {
  const int t = blockIdx.x;                    // 0..TOK-1
  const int tid = threadIdx.x;
  const int d = tid & 31, g = tid >> 5;        // g 0..7
  const float c = cosp[t * 64 + d];
  const float s = sinp[t * 64 + d];
  bf16* row = qkv + (size_t)t * QKVN;
#pragma unroll
  for (int i = 0; i < 4; ++i) {
    bf16* p = row + (g + i * 8) * 64 + d;      // q heads
    float x1 = (float)p[0], x2 = (float)p[32];
    p[0]  = (bf16)(x1 * c - x2 * s);
    p[32] = (bf16)(x2 * c + x1 * s);
  }
  bf16* p = row + 2048 + g * 64 + d;           // k head
  float x1 = (float)p[0], x2 = (float)p[32];
  p[0]  = (bf16)(x1 * c - x2 * s);
  p[32] = (bf16)(x2 * c + x1 * s);
}

// ---------------- transpose V: qkv v-cols -> vT[(b*8+kv)][64][2048] ----------
__global__ __launch_bounds__(256) void transpose_v(const bf16* __restrict__ v,  // qkv + 2560
                                                   bf16* __restrict__ vT) {
  __shared__ __align__(16) bf16 t[64][72];
  const int bkv = blockIdx.y;
  const int b = bkv >> 3, kv = bkv & 7;
  const int s0 = blockIdx.x * 64;
  const int tid = threadIdx.x;
  const int r = tid >> 3, c = (tid & 7) * 8;
#pragma unroll
  for (int p = 0; p < 2; ++p) {
    int rr = r + p * 32;
    *(bf16x8*)&t[rr][c] = *(const bf16x8*)&v[(size_t)(b * S_ + s0 + rr) * QKVN + kv * 64 + c];
  }
  __syncthreads();
#pragma unroll
  for (int p = 0; p < 2; ++p) {
    int d = r + p * 32;
    bf16x8 o;
#pragma unroll
    for (int j = 0; j < 8; ++j) o[j] = t[c + j][d];
    *(bf16x8*)&vT[((size_t)bkv * 64 + d) * S_ + s0 + c] = o;
  }
}

// ---------------- fused causal attention (stripe-paired, 4 waves) ----------------
// block = (qt, bh): stripes LO = qt*64 and HI = (31-qt)*64 of one (b,h).
// SWAPPED QK^T: acc = mfma(K_frag, Q_frag) -> lane holds P[q=fr][k=nn*16+fg*4+r].
// Raw barriers (BAR_LGKM): stores never drained at barriers -> write pipe
// overlaps compute. Order: k0-prefetch, zero-fill (background), pass1 (K dbuf),
// pass2 (recompute, f32x4 cached P stores, PV accumulate).
__global__ __launch_bounds__(256, 4) void attn_kernel(const bf16* __restrict__ qkv, // (TOK, 3072)
                                                      const bf16* __restrict__ vT,  // (16,64,2048)
                                                      float* __restrict__ attnw,    // (64, S, S)
                                                      bf16* __restrict__ attn_out)  // (TOK, 2048)
{
  __shared__ __align__(16) bf16 Ks2[2][64][72];
  __shared__ __align__(16) bf16 Vs[64][72];
  __shared__ __align__(16) bf16 Ps[4][16][72];

  const int tid  = threadIdx.x;
  const int wave = tid >> 6, lane = tid & 63;
  const int qt = blockIdx.x;                   // 0..15
  const int bh = blockIdx.y;                   // 0..63
  const int b = bh >> 5, h = bh & 31, kv = h >> 2;
  const int qLo = qt * 64;                     // LO stripe base row
  const int qHi = (31 - qt) * 64;              // HI stripe base row
  const int NT  = 32 - qt;                     // K/V tiles staged (HI needs all)
  const int fr = lane & 15, fg = lane >> 4;
  const int rw = wave * 16;                    // wave's row base within stripe
  const int rt = rw + fg * 4;                  // attn_out row group
  const int thr = rw + fr;                     // lane's q-row within stripe (diag threshold)

  // staging geometry: 256 threads, 64 rows x 64 cols bf16 per tile
  const int lr = tid >> 2;                     // 0..63
  const int lc = (tid & 3) * 16;               // 0,16,32,48
  const bf16* kbase = qkv + (size_t)(b * S_) * QKVN + 2048 + kv * 64;
  const bf16* vbase = vT + (size_t)(b * NKV_ + kv) * 64 * S_;
  const bf16* kst = kbase + (size_t)lr * QKVN + lc;   // + jt*64*QKVN
  const bf16* vst = vbase + (size_t)lr * S_ + lc;     // + jt*64

  // tile-0 K loads FIRST (in-order vmcnt: retire before the zero-fill stores)
  bf16x8 kr0 = *(const bf16x8*)(kst);
  bf16x8 kr1 = *(const bf16x8*)(kst + 8);

  // Q fragments for both stripes (K=64 -> 2 chunks of 32); used as MFMA B-operand.
  bf16x8 aqL[2], aqH[2];
  {
    const bf16* qp = qkv + (size_t)(b * S_ + qLo + rw + fr) * QKVN + h * 64 + fg * 8;
    aqL[0] = *(const bf16x8*)qp;  aqL[1] = *(const bf16x8*)(qp + 32);
    qp = qkv + (size_t)(b * S_ + qHi + rw + fr) * QKVN + h * 64 + fg * 8;
    aqH[0] = *(const bf16x8*)qp;  aqH[1] = *(const bf16x8*)(qp + 32);
  }

  // ---------- zero-fill masked regions (background NT stores) ----------
  {
    f32x4 z4 = {0.f, 0.f, 0.f, 0.f};
    const int zLo = (qt + 1) * 64;              // LO rows: cols [zLo, S)
    for (int rr = 0; rr < 16; ++rr) {
      size_t base = ((size_t)bh * S_ + qLo + rw + rr) * S_;
      for (int c = zLo + lane * 4; c < S_; c += 256)
        __builtin_nontemporal_store(z4, (f32x4*)&attnw[base + c]);
    }
    const int zHi = NT * 64;                    // HI rows: cols [zHi, S)
    for (int rr = 0; rr < 16; ++rr) {
      size_t base = ((size_t)bh * S_ + qHi + rw + rr) * S_;
      for (int c = zHi + lane * 4; c < S_; c += 256)
        __builtin_nontemporal_store(z4, (f32x4*)&attnw[base + c]);
    }
  }

  // ---------- pass 1: rowsums of exp(logit), K double-buffered ----------
  float rsL = 0.f, rsH = 0.f;                  // scalar: lane owns q-row fr
  {
    *(bf16x8*)&Ks2[0][lr][lc]     = kr0;
    *(bf16x8*)&Ks2[0][lr][lc + 8] = kr1;
    BAR_LGKM();
    for (int jt = 0; jt < NT; ++jt) {
      const int cur = jt & 1;
      if (jt + 1 < NT) {                        // prefetch next tile to regs
        const bf16* p = kst + (size_t)(jt + 1) * 64 * QKVN;
        kr0 = *(const bf16x8*)(p);
        kr1 = *(const bf16x8*)(p + 8);
      }
      // HI stripe (always active)
      {
        f32x4 acc[4] = {};
#pragma unroll
        for (int nn = 0; nn < 4; ++nn) {
          bf16x8 bk0 = *(const bf16x8*)&Ks2[cur][nn*16 + fr][fg*8];
          bf16x8 bk1 = *(const bf16x8*)&Ks2[cur][nn*16 + fr][32 + fg*8];
          acc[nn] = __builtin_amdgcn_mfma_f32_16x16x32_bf16(bk0, aqH[0], acc[nn], 0, 0, 0);
          acc[nn] = __builtin_amdgcn_mfma_f32_16x16x32_bf16(bk1, aqH[1], acc[nn], 0, 0, 0);
        }
        if (jt < NT - 1) {                      // fully unmasked
#pragma unroll
          for (int nn = 0; nn < 4; ++nn)
#pragma unroll
            for (int r = 0; r < 4; ++r) rsH += __expf(acc[nn][r] * 0.125f);
        } else {                                // HI diagonal tile: k <= q
#pragma unroll
          for (int nn = 0; nn < 4; ++nn)
#pragma unroll
            for (int r = 0; r < 4; ++r)
              if (nn * 16 + fg * 4 + r <= thr) rsH += __expf(acc[nn][r] * 0.125f);
        }
      }
      // LO stripe (active for jt <= qt; block-uniform)
      if (jt <= qt) {
        f32x4 acc[4] = {};
#pragma unroll
        for (int nn = 0; nn < 4; ++nn) {
          bf16x8 bk0 = *(const bf16x8*)&Ks2[cur][nn*16 + fr][fg*8];
          bf16x8 bk1 = *(const bf16x8*)&Ks2[cur][nn*16 + fr][32 + fg*8];
          acc[nn] = __builtin_amdgcn_mfma_f32_16x16x32_bf16(bk0, aqL[0], acc[nn], 0, 0, 0);
          acc[nn] = __builtin_amdgcn_mfma_f32_16x16x32_bf16(bk1, aqL[1], acc[nn], 0, 0, 0);
        }
        if (jt < qt) {
#pragma unroll
          for (int nn = 0; nn < 4; ++nn)
#pragma unroll
            for (int r = 0; r < 4; ++r) rsL += __expf(acc[nn][r] * 0.125f);
        } else {                                // LO diagonal tile
#pragma unroll
          for (int nn = 0; nn < 4; ++nn)
#pragma unroll
            for (int r = 0; r < 4; ++r)
              if (nn * 16 + fg * 4 + r <= thr) rsL += __expf(acc[nn][r] * 0.125f);
        }
      }
      if (jt + 1 < NT) {                        // stage next tile, ONE barrier
        *(bf16x8*)&Ks2[cur ^ 1][lr][lc]     = kr0;
        *(bf16x8*)&Ks2[cur ^ 1][lr][lc + 8] = kr1;
        BAR_LGKM();
      }
    }
  }
  // reduce across the 4 fg lane-groups (k-partitions), then invert
  {
    float v = rsL;
    v += __shfl_xor(v, 16); v += __shfl_xor(v, 32);
    rsL = 1.0f / v;
    v = rsH;
    v += __shfl_xor(v, 16); v += __shfl_xor(v, 32);
    rsH = 1.0f / v;
  }

  // ---------- pass 2: recompute (swapped), write P f32x4, accumulate O ----------
  f32x4 oL[4] = {}, oH[4] = {};
  {
    float* awpL = attnw + ((size_t)bh * S_ + qLo + rw + fr) * S_;   // lane's LO row
    float* awpH = attnw + ((size_t)bh * S_ + qHi + rw + fr) * S_;   // lane's HI row
    const int cb = fg * 4;                      // lane's 4-col base within 16-window
    kr0 = *(const bf16x8*)(kst);               // prefetch tile 0
    kr1 = *(const bf16x8*)(kst + 8);
    bf16x8 vr0 = *(const bf16x8*)(vst);
    bf16x8 vr1 = *(const bf16x8*)(vst + 8);
    for (int jt = 0; jt < NT; ++jt) {
      const int j0 = jt * 64;
      BAR_LGKM();                               // all waves done reading prev tile
      *(bf16x8*)&Ks2[0][lr][lc]     = kr0;
      *(bf16x8*)&Ks2[0][lr][lc + 8] = kr1;
      *(bf16x8*)&Vs[lr][lc]     = vr0;
      *(bf16x8*)&Vs[lr][lc + 8] = vr1;
      BAR_LGKM();                               // stage visible
      if (jt + 1 < NT) {                        // loads issued BEFORE this tile's stores
        const bf16* p = kst + (size_t)(jt + 1) * 64 * QKVN;
        kr0 = *(const bf16x8*)(p);
        kr1 = *(const bf16x8*)(p + 8);
        p = vst + (size_t)(jt + 1) * 64;
        vr0 = *(const bf16x8*)(p);
        vr1 = *(const bf16x8*)(p + 8);
      }
      // ---- HI stripe (always) ----
      {
        f32x4 acc[4] = {};
#pragma unroll
        for (int nn = 0; nn < 4; ++nn) {
          bf16x8 bk0 = *(const bf16x8*)&Ks2[0][nn*16 + fr][fg*8];
          bf16x8 bk1 = *(const bf16x8*)&Ks2[0][nn*16 + fr][32 + fg*8];
          acc[nn] = __builtin_amdgcn_mfma_f32_16x16x32_bf16(bk0, aqH[0], acc[nn], 0, 0, 0);
          acc[nn] = __builtin_amdgcn_mfma_f32_16x16x32_bf16(bk1, aqH[1], acc[nn], 0, 0, 0);
        }
        const bool diag = (jt == NT - 1);
#pragma unroll
        for (int nn = 0; nn < 4; ++nn) {
          f32x4 pv;
          bf16x4 pb;
#pragma unroll
          for (int r = 0; r < 4; ++r) {
            float e = __expf(acc[nn][r] * 0.125f) * rsH;
            pv[r] = (diag && (nn * 16 + cb + r > thr)) ? 0.f : e;
            pb[r] = (bf16)pv[r];
          }
          *(f32x4*)&awpH[j0 + nn * 16 + cb] = pv;   // plain cached store
          *(bf16x4*)&Ps[wave][fr][nn * 16 + cb] = pb;
        }
        bf16x8 pa0 = *(const bf16x8*)&Ps[wave][fr][fg * 8];
        bf16x8 pa1 = *(const bf16x8*)&Ps[wave][fr][32 + fg * 8];
#pragma unroll
        for (int nn = 0; nn < 4; ++nn) {
          bf16x8 bv0 = *(const bf16x8*)&Vs[nn*16 + fr][fg*8];
          bf16x8 bv1 = *(const bf16x8*)&Vs[nn*16 + fr][32 + fg*8];
          oH[nn] = __builtin_amdgcn_mfma_f32_16x16x32_bf16(pa0, bv0, oH[nn], 0, 0, 0);
          oH[nn] = __builtin_amdgcn_mfma_f32_16x16x32_bf16(pa1, bv1, oH[nn], 0, 0, 0);
        }
      }
      // ---- LO stripe (jt <= qt; block-uniform) ----
      if (jt <= qt) {
        f32x4 acc[4] = {};
#pragma unroll
        for (int nn = 0; nn < 4; ++nn) {
          bf16x8 bk0 = *(const bf16x8*)&Ks2[0][nn*16 + fr][fg*8];
          bf16x8 bk1 = *(const bf16x8*)&Ks2[0][nn*16 + fr][32 + fg*8];
          acc[nn] = __builtin_amdgcn_mfma_f32_16x16x32_bf16(bk0, aqL[0], acc[nn], 0, 0, 0);
          acc[nn] = __builtin_amdgcn_mfma_f32_16x16x32_bf16(bk1, aqL[1], acc[nn], 0, 0, 0);
        }
        const bool diag = (jt == qt);
#pragma unroll
        for (int nn = 0; nn < 4; ++nn) {
          f32x4 pv;
          bf16x4 pb;
#pragma unroll
          for (int r = 0; r < 4; ++r) {
            float e = __expf(acc[nn][r] * 0.125f) * rsL;
            pv[r] = (diag && (nn * 16 + cb + r > thr)) ? 0.f : e;
            pb[r] = (bf16)pv[r];
          }
          *(f32x4*)&awpL[j0 + nn * 16 + cb] = pv;   // plain cached store
          *(bf16x4*)&Ps[wave][fr][nn * 16 + cb] = pb;
        }
        bf16x8 pa0 = *(const bf16x8*)&Ps[wave][fr][fg * 8];
        bf16x8 pa1 = *(const bf16x8*)&Ps[wave][fr][32 + fg * 8];
#pragma unroll
        for (int nn = 0; nn < 4; ++nn) {
          bf16x8 bv0 = *(const bf16x8*)&Vs[nn*16 + fr][fg*8];
          bf16x8 bv1 = *(const bf16x8*)&Vs[nn*16 + fr][32 + fg*8];
          oL[nn] = __builtin_amdgcn_mfma_f32_16x16x32_bf16(pa0, bv0, oL[nn], 0, 0, 0);
          oL[nn] = __builtin_amdgcn_mfma_f32_16x16x32_bf16(pa1, bv1, oL[nn], 0, 0, 0);
        }
      }
    }
  }

  // attn_out (bf16) for both stripes (PV D-layout: row q = rt+r, col d = nn*16+fr)
#pragma unroll
  for (int nn = 0; nn < 4; ++nn)
#pragma unroll
    for (int r = 0; r < 4; ++r) {
      int rowL = qLo + rt + r;
      int rowH = qHi + rt + r;
      attn_out[(size_t)(b * S_ + rowL) * (NH_*HD_) + h * 64 + nn * 16 + fr] = (bf16)oL[nn][r];
      attn_out[(size_t)(b * S_ + rowH) * (NH_*HD_) + h * 64 + nn * 16 + fr] = (bf16)oH[nn][r];
    }
}

// ---------------------------------------------------------------------------
extern "C" void kernel_launch(void* const* d_in, const int* in_sizes, int n_in,
                              void* d_out, int out_size, void* d_ws, size_t ws_size,
                              hipStream_t stream) {
  const float* hs   = (const float*)d_in[0];
  const float* cosp = (const float*)d_in[1];
  const float* sinp = (const float*)d_in[2];
  // d_in[3] = attention_mask (causal; applied analytically)
  const float* Wq = (const float*)d_in[4];
  const float* Wk = (const float*)d_in[5];
  const float* Wv = (const float*)d_in[6];
  const float* Wo = (const float*)d_in[7];

  char* ws = (char*)d_ws;
  bf16* hs_b   = (bf16*)(ws);                   // 16 MB
  bf16* qkv_b  = (bf16*)(ws + (16u << 20));     // 24 MB (TOK x 3072)
  bf16* vT_b   = (bf16*)(ws + (40u << 20));     // 4 MB
  bf16* ao_b   = (bf16*)(ws + (44u << 20));     // 16 MB
  bf16* Wqkv_b = (bf16*)(ws + (60u << 20));     // 12 MB (3072 x 2048)
  bf16* Wo_b   = (bf16*)(ws + (72u << 20));     // 8 MB

  float* outp  = (float*)d_out;
  float* attnw = outp + (size_t)TOK_ * HID_;    // + 8388608

  // casts to bf16
  cast_f32_bf16<<<(TOK_*HID_/4 + 255)/256, 256, 0, stream>>>(hs, hs_b, TOK_*HID_/4);
  cast_wqkv<<<(1572864 + 255)/256, 256, 0, stream>>>(Wq, Wk, Wv, Wqkv_b);
  cast_f32_bf16<<<(HID_*NH_*HD_/4 + 255)/256, 256, 0, stream>>>(Wo, Wo_b, HID_*NH_*HD_/4);

  // fused QKV projection: (TOK,2048) @ (3072,2048)^T -> (TOK,3072)
  gemm_bt<false><<<dim3(QKVN/128, TOK_/128), 256, 0, stream>>>(hs_b, Wqkv_b, qkv_b, TOK_, QKVN, HID_);

  // RoPE (in place, one block per token)
  rope_fused<<<TOK_, 256, 0, stream>>>(qkv_b, cosp, sinp);

  // V transpose for PV B-operand contiguity
  transpose_v<<<dim3(S_/64, B_*NKV_), 256, 0, stream>>>(qkv_b + 2560, vT_b);

  // fused attention (stripe-paired; writes attn_weights f32 + attn_out bf16)
  attn_kernel<<<dim3(S_/128, B_*NH_), 256, 0, stream>>>(qkv_b, vT_b, attnw, ao_b);

  // output projection (f32 out)
  gemm_bt<true><<<dim3(HID_/128, TOK_/128), 256, 0, stream>>>(ao_b, Wo_b, outp, TOK_, HID_, HID_);
}